// Round 1
// baseline (936.527 us; speedup 1.0000x reference)
//
#include <hip/hip_runtime.h>
#include <hip/hip_bf16.h>

// ---------------------------------------------------------------------------
// RGAT: 2x RGATConv (R=8, H=128, heads=1) + mean/max pool + MLP head -> scalar
//
// Structure:
//   CSR build (by dst): hist -> scan -> scatter           [once, edges shared]
//   per layer:
//     Wq[r]=W[r]@q, Wk[r]=W[r]@k                          [tiny]
//     qv[n,r]=x[n]·Wq[r], kv[n,r]=x[n]·Wk[r]              [wave/node]
//     per-node softmax + aggregate: agg[n, r*128+i] = sum att*x[src][i]
//     GEMM out = agg[N,1024] @ W[1024,128] + b, relu
//   pool (mean+max) -> tanh -> fc1 relu -> fc2 -> sigmoid
// ---------------------------------------------------------------------------

#define SCHUNK 1024

__global__ __launch_bounds__(256) void k_hist(const int* __restrict__ dst, int* __restrict__ cnt, int E) {
  int e = blockIdx.x * 256 + threadIdx.x;
  if (e < E) atomicAdd(&cnt[dst[e]], 1);
}

__global__ __launch_bounds__(256) void k_chunk_sums(const int* __restrict__ cnt, int* __restrict__ sums, int n) {
  __shared__ int sd[256];
  int base = blockIdx.x * SCHUNK;
  int t = threadIdx.x;
  int s = 0;
  for (int i = t; i < SCHUNK; i += 256) { int idx = base + i; if (idx < n) s += cnt[idx]; }
  sd[t] = s; __syncthreads();
  for (int off = 128; off; off >>= 1) { if (t < off) sd[t] += sd[t + off]; __syncthreads(); }
  if (t == 0) sums[blockIdx.x] = sd[0];
}

__global__ void k_scan_sums(int* sums, int nchunks) {
  __shared__ int sh[64];
  int t = threadIdx.x;
  sh[t] = (t < nchunks) ? sums[t] : 0;
  __syncthreads();
  if (t == 0) { int acc = 0; for (int i = 0; i < nchunks; i++) { int v = sh[i]; sh[i] = acc; acc += v; } }
  __syncthreads();
  if (t < nchunks) sums[t] = sh[t];
}

__global__ __launch_bounds__(256) void k_scan_write(const int* __restrict__ cnt, const int* __restrict__ sums,
                                                    int* __restrict__ row_ptr, int n, int total) {
  __shared__ int sd[256];
  int b = blockIdx.x, t = threadIdx.x;
  int base = b * SCHUNK + t * 4;
  int v0 = 0, v1 = 0, v2 = 0, v3 = 0;
  if (base + 0 < n) v0 = cnt[base + 0];
  if (base + 1 < n) v1 = cnt[base + 1];
  if (base + 2 < n) v2 = cnt[base + 2];
  if (base + 3 < n) v3 = cnt[base + 3];
  int s = v0 + v1 + v2 + v3;
  sd[t] = s; __syncthreads();
  for (int off = 1; off < 256; off <<= 1) {
    int x = 0; if (t >= off) x = sd[t - off];
    __syncthreads();
    sd[t] += x;
    __syncthreads();
  }
  int run = sums[b] + sd[t] - s;  // exclusive prefix for this thread's 4 elems
  if (base + 0 < n) { row_ptr[base + 0] = run; run += v0; }
  if (base + 1 < n) { row_ptr[base + 1] = run; run += v1; }
  if (base + 2 < n) { row_ptr[base + 2] = run; run += v2; }
  if (base + 3 < n) { row_ptr[base + 3] = run; run += v3; }
  if (b == 0 && t == 0) row_ptr[n] = total;
}

__global__ __launch_bounds__(256) void k_scatter(const int* __restrict__ src, const int* __restrict__ dst,
                                                 const int* __restrict__ et, int* __restrict__ cursor,
                                                 int* __restrict__ srcs, int* __restrict__ ets, int E) {
  int e = blockIdx.x * 256 + threadIdx.x;
  if (e >= E) return;
  int d = dst[e];
  int p = atomicAdd(&cursor[d], 1);
  srcs[p] = src[e];
  ets[p] = et[e];
}

// Wq[r][i] = sum_o W[r][i][o]*q[o]; Wk likewise. grid=8 blocks, 128 threads.
__global__ void k_wqk(const float* __restrict__ W, const float* __restrict__ q, const float* __restrict__ k,
                      float* __restrict__ wq, float* __restrict__ wk) {
  int r = blockIdx.x, i = threadIdx.x;
  const float* wrow = W + (size_t)r * 16384 + (size_t)i * 128;
  float aq = 0.f, ak = 0.f;
  for (int o = 0; o < 128; o++) { float wv = wrow[o]; aq += wv * q[o]; ak += wv * k[o]; }
  wq[r * 128 + i] = aq;
  wk[r * 128 + i] = ak;
}

// qv[n][r] = x[n]·wq[r]. One wave per node; block = 4 waves.
__global__ __launch_bounds__(256) void k_qvkv(const float* __restrict__ xin, const float* __restrict__ wq,
                                              const float* __restrict__ wk, float* __restrict__ qv,
                                              float* __restrict__ kv, int N) {
  __shared__ float swq[1024], swk[1024];
  for (int i = threadIdx.x; i < 1024; i += 256) { swq[i] = wq[i]; swk[i] = wk[i]; }
  __syncthreads();
  int lane = threadIdx.x & 63;
  int n = blockIdx.x * 4 + (threadIdx.x >> 6);
  if (n >= N) return;
  float2 xv = ((const float2*)xin)[(size_t)n * 64 + lane];
  #pragma unroll
  for (int r = 0; r < 8; r++) {
    float pq = xv.x * swq[r * 128 + 2 * lane] + xv.y * swq[r * 128 + 2 * lane + 1];
    float pk = xv.x * swk[r * 128 + 2 * lane] + xv.y * swk[r * 128 + 2 * lane + 1];
    #pragma unroll
    for (int off = 32; off; off >>= 1) {
      pq += __shfl_xor(pq, off, 64);
      pk += __shfl_xor(pk, off, 64);
    }
    if (lane == 0) { qv[(size_t)n * 8 + r] = pq; kv[(size_t)n * 8 + r] = pk; }
  }
}

// Per-node softmax + weighted aggregation into agg[node_local][1024].
// One wave per node. Lane handles channels 2*lane, 2*lane+1.
__global__ __launch_bounds__(256) void k_agg(const int* __restrict__ row_ptr, const int* __restrict__ srcs,
                                             const int* __restrict__ ets, const float* __restrict__ qv,
                                             const float* __restrict__ kv, const float* __restrict__ xin,
                                             float* __restrict__ agg, int n0, int cnt) {
  int wid = ((blockIdx.x * 256 + threadIdx.x) >> 6);
  int lane = threadIdx.x & 63;
  if (wid >= cnt) return;
  int n = n0 + wid;
  int start = row_ptr[n], end = row_ptr[n + 1];
  const float2* x2 = (const float2*)xin;
  // pass 1: max of leaky_relu(qv[n][r] + kv[s][r]) over incoming edges
  float m = -1e30f;
  for (int p = start + lane; p < end; p += 64) {
    int s = srcs[p]; int r = ets[p];
    float a = qv[(size_t)n * 8 + r] + kv[(size_t)s * 8 + r];
    a = (a >= 0.f) ? a : 0.2f * a;
    m = fmaxf(m, a);
  }
  #pragma unroll
  for (int off = 32; off; off >>= 1) m = fmaxf(m, __shfl_xor(m, off, 64));
  // pass 2: serial over edges; accumulate exp(a-m)*x[src] per relation
  float denom = 0.f;
  float2 acc[8];
  #pragma unroll
  for (int r = 0; r < 8; r++) acc[r] = make_float2(0.f, 0.f);
  for (int p = start; p < end; ++p) {
    int s = srcs[p]; int r = ets[p];         // wave-uniform loads
    float a = qv[(size_t)n * 8 + r] + kv[(size_t)s * 8 + r];
    a = (a >= 0.f) ? a : 0.2f * a;
    float w = __expf(a - m);
    denom += w;
    float2 xv = x2[(size_t)s * 64 + lane];   // coalesced 512B row
    #pragma unroll
    for (int rr = 0; rr < 8; rr++)
      if (r == rr) { acc[rr].x += w * xv.x; acc[rr].y += w * xv.y; }  // wave-uniform branch
  }
  float inv = 1.f / (denom + 1e-16f);
  float2* ag2 = (float2*)agg;
  size_t bptr = (size_t)wid * 512;
  #pragma unroll
  for (int rr = 0; rr < 8; rr++) {
    ag2[bptr + rr * 64 + lane] = make_float2(acc[rr].x * inv, acc[rr].y * inv);
  }
}

// C[M,128] = relu(A[M,1024] @ B[1024,128] + bias). BM=64, BN=128, BK=16.
__global__ __launch_bounds__(256) void k_gemm(const float* __restrict__ A, const float* __restrict__ B,
                                              const float* __restrict__ bias, float* __restrict__ C, int M) {
  __shared__ float As[16][64 + 4];
  __shared__ float Bs[16][128 + 4];
  int bm = blockIdx.x * 64;
  int tid = threadIdx.x;
  int tx = tid & 15, ty = tid >> 4;
  float acc[4][8];
  #pragma unroll
  for (int i = 0; i < 4; i++)
    #pragma unroll
    for (int j = 0; j < 8; j++) acc[i][j] = 0.f;
  int la_m = tid >> 2;
  int la_k = (tid & 3) * 4;
  int lb_k = tid >> 4;
  int lb_n = (tid & 15) * 8;
  for (int k0 = 0; k0 < 1024; k0 += 16) {
    float4 av = make_float4(0.f, 0.f, 0.f, 0.f);
    if (bm + la_m < M) av = *(const float4*)(A + (size_t)(bm + la_m) * 1024 + k0 + la_k);
    As[la_k + 0][la_m] = av.x; As[la_k + 1][la_m] = av.y;
    As[la_k + 2][la_m] = av.z; As[la_k + 3][la_m] = av.w;
    float4 bv0 = *(const float4*)(B + (size_t)(k0 + lb_k) * 128 + lb_n);
    float4 bv1 = *(const float4*)(B + (size_t)(k0 + lb_k) * 128 + lb_n + 4);
    Bs[lb_k][lb_n + 0] = bv0.x; Bs[lb_k][lb_n + 1] = bv0.y;
    Bs[lb_k][lb_n + 2] = bv0.z; Bs[lb_k][lb_n + 3] = bv0.w;
    Bs[lb_k][lb_n + 4] = bv1.x; Bs[lb_k][lb_n + 5] = bv1.y;
    Bs[lb_k][lb_n + 6] = bv1.z; Bs[lb_k][lb_n + 7] = bv1.w;
    __syncthreads();
    #pragma unroll
    for (int kk = 0; kk < 16; kk++) {
      float a0 = As[kk][ty * 4 + 0];
      float a1 = As[kk][ty * 4 + 1];
      float a2 = As[kk][ty * 4 + 2];
      float a3 = As[kk][ty * 4 + 3];
      float bvl[8];
      #pragma unroll
      for (int j = 0; j < 8; j++) bvl[j] = Bs[kk][tx * 8 + j];
      #pragma unroll
      for (int j = 0; j < 8; j++) {
        acc[0][j] += a0 * bvl[j];
        acc[1][j] += a1 * bvl[j];
        acc[2][j] += a2 * bvl[j];
        acc[3][j] += a3 * bvl[j];
      }
    }
    __syncthreads();
  }
  #pragma unroll
  for (int i = 0; i < 4; i++) {
    int m = bm + ty * 4 + i;
    if (m < M) {
      #pragma unroll
      for (int j = 0; j < 8; j++) {
        float v = acc[i][j] + bias[tx * 8 + j];
        C[(size_t)m * 128 + tx * 8 + j] = v > 0.f ? v : 0.f;
      }
    }
  }
}

// mean+max pool over nodes. h >= 0 (post-relu) so int-cmp atomicMax on float bits works.
__global__ __launch_bounds__(256) void k_pool(const float* __restrict__ h, float* __restrict__ gsum,
                                              float* __restrict__ gmax, int N) {
  int c = threadIdx.x & 127;
  int half = threadIdx.x >> 7;
  float s = 0.f, m = 0.f;
  for (int n = blockIdx.x * 2 + half; n < N; n += gridDim.x * 2) {
    float v = h[(size_t)n * 128 + c];
    s += v; m = fmaxf(m, v);
  }
  __shared__ float ss[256], sm[256];
  ss[threadIdx.x] = s; sm[threadIdx.x] = m;
  __syncthreads();
  if (half == 0) {
    s += ss[threadIdx.x + 128];
    m = fmaxf(m, sm[threadIdx.x + 128]);
    atomicAdd(&gsum[c], s);
    atomicMax((int*)gmax + c, __float_as_int(m));
  }
}

__global__ void k_head(const float* __restrict__ gsum, const float* __restrict__ gmax,
                       const float* __restrict__ fc1w, const float* __restrict__ fc1b,
                       const float* __restrict__ fc2w, const float* __restrict__ fc2b,
                       float* __restrict__ out, int N) {
  __shared__ float g[256];
  __shared__ float red[128];
  int t = threadIdx.x;
  if (t < 128) g[t] = tanhf(gsum[t] / (float)N);
  else g[t] = tanhf(gmax[t - 128]);
  __syncthreads();
  float r1 = 0.f;
  if (t < 128) {
    float a = fc1b[t];
    for (int i = 0; i < 256; i++) a += g[i] * fc1w[i * 128 + t];
    r1 = a > 0.f ? a : 0.f;
    red[t] = r1 * fc2w[t];
  }
  __syncthreads();
  for (int s = 64; s > 0; s >>= 1) {
    if (t < s) red[t] += red[t + s];
    __syncthreads();
  }
  if (t == 0) {
    float o = red[0] + fc2b[0];
    out[0] = 1.f / (1.f + __expf(-o));
  }
}

extern "C" void kernel_launch(void* const* d_in, const int* in_sizes, int n_in,
                              void* d_out, int out_size, void* d_ws, size_t ws_size,
                              hipStream_t stream) {
  const float* x    = (const float*)d_in[0];
  const int*   ei   = (const int*)d_in[1];
  const int*   ety  = (const int*)d_in[2];
  const float* w0   = (const float*)d_in[3];
  const float* q0   = (const float*)d_in[4];
  const float* k0   = (const float*)d_in[5];
  const float* b0   = (const float*)d_in[6];
  const float* w1   = (const float*)d_in[7];
  const float* q1   = (const float*)d_in[8];
  const float* k1   = (const float*)d_in[9];
  const float* b1   = (const float*)d_in[10];
  const float* fc1w = (const float*)d_in[11];
  const float* fc1b = (const float*)d_in[12];
  const float* fc2w = (const float*)d_in[13];
  const float* fc2b = (const float*)d_in[14];
  int N = in_sizes[0] / 128;
  int E = in_sizes[2];
  const int* src = ei;
  const int* dst = ei + E;

  char* base = (char*)d_ws;
  size_t off = 0;
  auto alloc = [&](size_t bytes) -> void* {
    off = (off + 255) & ~(size_t)255;
    void* p = base + off;
    off += bytes;
    return p;
  };
  int*   row_ptr = (int*)alloc((size_t)(N + 1) * 4);
  int*   cursor  = (int*)alloc((size_t)N * 4);       // doubles as histogram cnt
  int*   srcs    = (int*)alloc((size_t)E * 4);
  int*   ets     = (int*)alloc((size_t)E * 4);
  int*   csums   = (int*)alloc(64 * 4);
  float* wq      = (float*)alloc(1024 * 4);
  float* wk      = (float*)alloc(1024 * 4);
  float* qv      = (float*)alloc((size_t)N * 8 * 4);
  float* kv      = (float*)alloc((size_t)N * 8 * 4);
  float* h1      = (float*)alloc((size_t)N * 128 * 4);
  float* h2      = (float*)alloc((size_t)N * 128 * 4);
  float* gsum    = (float*)alloc(128 * 4);
  float* gmax    = (float*)alloc(128 * 4);
  off = (off + 255) & ~(size_t)255;
  float* agg = (float*)(base + off);
  size_t avail = (ws_size > off) ? (ws_size - off) : 0;
  int chunk = (int)(avail / 4096);   // 1024 floats per node
  if (chunk > N) chunk = N;
  if (chunk < 1) chunk = 1;

  int nchunks = (N + SCHUNK - 1) / SCHUNK;
  hipMemsetAsync(cursor, 0, (size_t)N * 4, stream);
  k_hist<<<(E + 255) / 256, 256, 0, stream>>>(dst, cursor, E);
  k_chunk_sums<<<nchunks, 256, 0, stream>>>(cursor, csums, N);
  k_scan_sums<<<1, 64, 0, stream>>>(csums, nchunks);
  k_scan_write<<<nchunks, 256, 0, stream>>>(cursor, csums, row_ptr, N, E);
  hipMemcpyAsync(cursor, row_ptr, (size_t)N * 4, hipMemcpyDeviceToDevice, stream);
  k_scatter<<<(E + 255) / 256, 256, 0, stream>>>(src, dst, ety, cursor, srcs, ets, E);

  for (int layer = 0; layer < 2; ++layer) {
    const float* W   = layer ? w1 : w0;
    const float* qq  = layer ? q1 : q0;
    const float* kk  = layer ? k1 : k0;
    const float* bb  = layer ? b1 : b0;
    const float* xin = layer ? h1 : x;
    float* hout      = layer ? h2 : h1;
    k_wqk<<<8, 128, 0, stream>>>(W, qq, kk, wq, wk);
    k_qvkv<<<(N + 3) / 4, 256, 0, stream>>>(xin, wq, wk, qv, kv, N);
    for (int n0 = 0; n0 < N; n0 += chunk) {
      int cnt = (N - n0 < chunk) ? (N - n0) : chunk;
      k_agg<<<(cnt + 3) / 4, 256, 0, stream>>>(row_ptr, srcs, ets, qv, kv, xin, agg, n0, cnt);
      k_gemm<<<(cnt + 63) / 64, 256, 0, stream>>>(agg, W, bb, hout + (size_t)n0 * 128, cnt);
    }
  }

  hipMemsetAsync(gsum, 0, 128 * 4, stream);
  hipMemsetAsync(gmax, 0, 128 * 4, stream);
  k_pool<<<256, 256, 0, stream>>>(h2, gsum, gmax, N);
  k_head<<<1, 256, 0, stream>>>(gsum, gmax, fc1w, fc1b, fc2w, fc2b, (float*)d_out, N);
}

// Round 2
// 561.759 us; speedup vs baseline: 1.6671x; 1.6671x over previous
//
#include <hip/hip_runtime.h>
#include <hip/hip_bf16.h>

// ---------------------------------------------------------------------------
// RGAT: 2x RGATConv (R=8, H=128) + mean/max pool + MLP head -> scalar
//
// R2 structure (transform-first + MFMA):
//   CSR build (by dst): hist -> scan -> scatter
//   xb = bf16(x)
//   per layer:
//     Wq[r]=W[r]@q, Wk[r]=W[r]@k;  qv/kv[n,r] = x[n]·Wq/Wk[r]   (f32)
//     WT[r][h][k] = bf16(W[r][k][h])
//     Y[r] = xin_b @ W[r]          (bf16 MFMA 16x16x32, f32 acc)
//     h[n] = relu(bias + sum_e att_e * Y[et_e][src_e])          (gather agg)
//   pool (mean+max) -> tanh -> fc1 relu -> fc2 -> sigmoid
// ---------------------------------------------------------------------------

typedef __bf16 bf16x8 __attribute__((ext_vector_type(8)));
typedef __bf16 bf16x4 __attribute__((ext_vector_type(4)));
typedef __bf16 bf16x2 __attribute__((ext_vector_type(2)));
typedef float f32x4 __attribute__((ext_vector_type(4)));

#define SCHUNK 1024

// ----------------------------- CSR build -----------------------------------

__global__ __launch_bounds__(256) void k_hist(const int* __restrict__ dst, int* __restrict__ cnt, int E) {
  int e = blockIdx.x * 256 + threadIdx.x;
  if (e < E) atomicAdd(&cnt[dst[e]], 1);
}

__global__ __launch_bounds__(256) void k_chunk_sums(const int* __restrict__ cnt, int* __restrict__ sums, int n) {
  __shared__ int sd[256];
  int base = blockIdx.x * SCHUNK;
  int t = threadIdx.x;
  int s = 0;
  for (int i = t; i < SCHUNK; i += 256) { int idx = base + i; if (idx < n) s += cnt[idx]; }
  sd[t] = s; __syncthreads();
  for (int off = 128; off; off >>= 1) { if (t < off) sd[t] += sd[t + off]; __syncthreads(); }
  if (t == 0) sums[blockIdx.x] = sd[0];
}

__global__ void k_scan_sums(int* sums, int nchunks) {
  __shared__ int sh[64];
  int t = threadIdx.x;
  sh[t] = (t < nchunks) ? sums[t] : 0;
  __syncthreads();
  if (t == 0) { int acc = 0; for (int i = 0; i < nchunks; i++) { int v = sh[i]; sh[i] = acc; acc += v; } }
  __syncthreads();
  if (t < nchunks) sums[t] = sh[t];
}

__global__ __launch_bounds__(256) void k_scan_write(const int* __restrict__ cnt, const int* __restrict__ sums,
                                                    int* __restrict__ row_ptr, int n, int total) {
  __shared__ int sd[256];
  int b = blockIdx.x, t = threadIdx.x;
  int base = b * SCHUNK + t * 4;
  int v0 = 0, v1 = 0, v2 = 0, v3 = 0;
  if (base + 0 < n) v0 = cnt[base + 0];
  if (base + 1 < n) v1 = cnt[base + 1];
  if (base + 2 < n) v2 = cnt[base + 2];
  if (base + 3 < n) v3 = cnt[base + 3];
  int s = v0 + v1 + v2 + v3;
  sd[t] = s; __syncthreads();
  for (int off = 1; off < 256; off <<= 1) {
    int x = 0; if (t >= off) x = sd[t - off];
    __syncthreads();
    sd[t] += x;
    __syncthreads();
  }
  int run = sums[b] + sd[t] - s;
  if (base + 0 < n) { row_ptr[base + 0] = run; run += v0; }
  if (base + 1 < n) { row_ptr[base + 1] = run; run += v1; }
  if (base + 2 < n) { row_ptr[base + 2] = run; run += v2; }
  if (base + 3 < n) { row_ptr[base + 3] = run; run += v3; }
  if (b == 0 && t == 0) row_ptr[n] = total;
}

__global__ __launch_bounds__(256) void k_scatter(const int* __restrict__ src, const int* __restrict__ dst,
                                                 const int* __restrict__ et, int* __restrict__ cursor,
                                                 int* __restrict__ srcs, int* __restrict__ ets, int E) {
  int e = blockIdx.x * 256 + threadIdx.x;
  if (e >= E) return;
  int d = dst[e];
  int p = atomicAdd(&cursor[d], 1);
  srcs[p] = src[e];
  ets[p] = et[e];
}

// ----------------------------- small precompute ------------------------------

__global__ void k_wqk(const float* __restrict__ W, const float* __restrict__ q, const float* __restrict__ k,
                      float* __restrict__ wq, float* __restrict__ wk) {
  int r = blockIdx.x, i = threadIdx.x;
  const float* wrow = W + (size_t)r * 16384 + (size_t)i * 128;
  float aq = 0.f, ak = 0.f;
  for (int o = 0; o < 128; o++) { float wv = wrow[o]; aq += wv * q[o]; ak += wv * k[o]; }
  wq[r * 128 + i] = aq;
  wk[r * 128 + i] = ak;
}

// WT[r][h][k] = bf16(W[r][k][h])
__global__ __launch_bounds__(128) void k_wt(const float* __restrict__ W, __bf16* __restrict__ WT) {
  int r = blockIdx.y, h = blockIdx.x, k = threadIdx.x;
  WT[((size_t)r * 128 + h) * 128 + k] = (__bf16)W[((size_t)r * 128 + k) * 128 + h];
}

__global__ __launch_bounds__(256) void k_cast(const float* __restrict__ src, __bf16* __restrict__ dst, int n4) {
  int i = blockIdx.x * 256 + threadIdx.x;
  if (i < n4) {
    float4 v = ((const float4*)src)[i];
    bf16x4 o;
    o.x = (__bf16)v.x; o.y = (__bf16)v.y; o.z = (__bf16)v.z; o.w = (__bf16)v.w;
    ((bf16x4*)dst)[i] = o;
  }
}

// qv[n][r] = x[n]·wq[r]. One wave per node; block = 4 waves. (f32 input)
__global__ __launch_bounds__(256) void k_qvkv(const float* __restrict__ xin, const float* __restrict__ wq,
                                              const float* __restrict__ wk, float* __restrict__ qv,
                                              float* __restrict__ kv, int N) {
  __shared__ float swq[1024], swk[1024];
  for (int i = threadIdx.x; i < 1024; i += 256) { swq[i] = wq[i]; swk[i] = wk[i]; }
  __syncthreads();
  int lane = threadIdx.x & 63;
  int n = blockIdx.x * 4 + (threadIdx.x >> 6);
  if (n >= N) return;
  float2 xv = ((const float2*)xin)[(size_t)n * 64 + lane];
  #pragma unroll
  for (int r = 0; r < 8; r++) {
    float pq = xv.x * swq[r * 128 + 2 * lane] + xv.y * swq[r * 128 + 2 * lane + 1];
    float pk = xv.x * swk[r * 128 + 2 * lane] + xv.y * swk[r * 128 + 2 * lane + 1];
    #pragma unroll
    for (int off = 32; off; off >>= 1) {
      pq += __shfl_xor(pq, off, 64);
      pk += __shfl_xor(pk, off, 64);
    }
    if (lane == 0) { qv[(size_t)n * 8 + r] = pq; kv[(size_t)n * 8 + r] = pk; }
  }
}

// --------------------------- MFMA transform GEMM -----------------------------
// Y[r][m][h] = sum_k A[m][k] * W[r][k][h],  A bf16 [M][128], WT[r][h][k] bf16.
// Block: 128 rows x 128 cols, 4 waves (wave w -> rows w*32..w*32+31).
// BK=64, 2 K-iters, single LDS buffer, padded stride 72 elems (144B, 16B mult).

#define LSTR 72

__global__ __launch_bounds__(256) void k_gemmY(const __bf16* __restrict__ A,
                                               const __bf16* __restrict__ WT,
                                               __bf16* __restrict__ Y, int M) {
  __shared__ __bf16 As[128 * LSTR];
  __shared__ __bf16 Bs[128 * LSTR];
  int r = blockIdx.y;
  int bm = blockIdx.x * 128;
  int tid = threadIdx.x;
  int w = tid >> 6, l = tid & 63;
  const __bf16* Br = WT + (size_t)r * 16384;

  f32x4 acc[2][8];
  #pragma unroll
  for (int m2 = 0; m2 < 2; ++m2)
    #pragma unroll
    for (int n2 = 0; n2 < 8; ++n2) acc[m2][n2] = (f32x4)0.f;

  int srow = tid >> 1;            // staging row 0..127
  int cbase = (tid & 1) * 4;      // 16B-chunk base within 64-elem row segment
  bool valid = (bm + srow) < M;

  for (int kt = 0; kt < 2; ++kt) {
    if (kt) __syncthreads();
    bf16x8 av[4], bv[4];
    const bf16x8* gA = (const bf16x8*)(A + (size_t)(bm + srow) * 128 + kt * 64);
    const bf16x8* gB = (const bf16x8*)(Br + (size_t)srow * 128 + kt * 64);
    #pragma unroll
    for (int i = 0; i < 4; ++i) {
      av[i] = valid ? gA[cbase + i] : (bf16x8)(__bf16)0.0f;
      bv[i] = gB[cbase + i];
    }
    #pragma unroll
    for (int i = 0; i < 4; ++i) {
      *(bf16x8*)&As[srow * LSTR + (cbase + i) * 8] = av[i];
      *(bf16x8*)&Bs[srow * LSTR + (cbase + i) * 8] = bv[i];
    }
    __syncthreads();
    #pragma unroll
    for (int ks = 0; ks < 2; ++ks) {
      bf16x8 af[2], bfv[8];
      #pragma unroll
      for (int m2 = 0; m2 < 2; ++m2)
        af[m2] = *(const bf16x8*)&As[(w * 32 + m2 * 16 + (l & 15)) * LSTR + ks * 32 + (l >> 4) * 8];
      #pragma unroll
      for (int n2 = 0; n2 < 8; ++n2)
        bfv[n2] = *(const bf16x8*)&Bs[(n2 * 16 + (l & 15)) * LSTR + ks * 32 + (l >> 4) * 8];
      #pragma unroll
      for (int m2 = 0; m2 < 2; ++m2)
        #pragma unroll
        for (int n2 = 0; n2 < 8; ++n2)
          acc[m2][n2] = __builtin_amdgcn_mfma_f32_16x16x32_bf16(af[m2], bfv[n2], acc[m2][n2], 0, 0, 0);
    }
  }

  // C/D layout: col = lane&15, row = (lane>>4)*4 + reg  (within 16x16 frag)
  __bf16* Yr = Y + ((size_t)r * M + bm) * 128;
  #pragma unroll
  for (int m2 = 0; m2 < 2; ++m2)
    #pragma unroll
    for (int j = 0; j < 4; ++j) {
      int row = w * 32 + m2 * 16 + (l >> 4) * 4 + j;
      if (bm + row < M) {
        #pragma unroll
        for (int n2 = 0; n2 < 8; ++n2)
          Yr[(size_t)row * 128 + n2 * 16 + (l & 15)] = (__bf16)acc[m2][n2][j];
      }
    }
}

// ------------------------- softmax + gather aggregate ------------------------
// One wave per node. out h[n] = relu(bias + sum_e att_e * Y[et][src]).

__global__ __launch_bounds__(256) void k_agg(const int* __restrict__ row_ptr, const int* __restrict__ srcs,
                                             const int* __restrict__ ets, const float* __restrict__ qv,
                                             const float* __restrict__ kv, const __bf16* __restrict__ Y,
                                             const float* __restrict__ bias, float* __restrict__ h,
                                             __bf16* __restrict__ hb, int N) {
  int wid = ((blockIdx.x * 256 + threadIdx.x) >> 6);
  int lane = threadIdx.x & 63;
  if (wid >= N) return;
  int n = wid;
  int start = row_ptr[n], end = row_ptr[n + 1];
  const float* qvn = qv + (size_t)n * 8;
  // pass 1: max over edges of leaky_relu(qv + kv)
  float m = -1e30f;
  for (int p = start + lane; p < end; p += 64) {
    int s = srcs[p]; int r = ets[p];
    float a = qvn[r] + kv[(size_t)s * 8 + r];
    a = (a >= 0.f) ? a : 0.2f * a;
    m = fmaxf(m, a);
  }
  #pragma unroll
  for (int off = 32; off; off >>= 1) m = fmaxf(m, __shfl_xor(m, off, 64));
  // pass 2: serial accumulate exp(a-m) * Y[r][s]
  float denom = 0.f, ax = 0.f, ay = 0.f;
  for (int p = start; p < end; ++p) {
    int s = srcs[p]; int r = ets[p];
    float a = qvn[r] + kv[(size_t)s * 8 + r];
    a = (a >= 0.f) ? a : 0.2f * a;
    float wgt = __expf(a - m);
    denom += wgt;
    bf16x2 yv = ((const bf16x2*)(Y + ((size_t)r * N + s) * 128))[lane];
    ax += wgt * (float)yv.x;
    ay += wgt * (float)yv.y;
  }
  float inv = 1.f / (denom + 1e-16f);
  float b0 = bias[2 * lane], b1 = bias[2 * lane + 1];
  float v0 = fmaxf(ax * inv + b0, 0.f);
  float v1 = fmaxf(ay * inv + b1, 0.f);
  ((float2*)(h + (size_t)n * 128))[lane] = make_float2(v0, v1);
  if (hb) {
    bf16x2 o; o.x = (__bf16)v0; o.y = (__bf16)v1;
    ((bf16x2*)(hb + (size_t)n * 128))[lane] = o;
  }
}

// ------------------------------- pool + head ---------------------------------

__global__ __launch_bounds__(256) void k_pool(const float* __restrict__ h, float* __restrict__ gsum,
                                              float* __restrict__ gmax, int N) {
  int c = threadIdx.x & 127;
  int half = threadIdx.x >> 7;
  float s = 0.f, m = 0.f;
  for (int n = blockIdx.x * 2 + half; n < N; n += gridDim.x * 2) {
    float v = h[(size_t)n * 128 + c];
    s += v; m = fmaxf(m, v);
  }
  __shared__ float ss[256], sm[256];
  ss[threadIdx.x] = s; sm[threadIdx.x] = m;
  __syncthreads();
  if (half == 0) {
    s += ss[threadIdx.x + 128];
    m = fmaxf(m, sm[threadIdx.x + 128]);
    atomicAdd(&gsum[c], s);
    atomicMax((int*)gmax + c, __float_as_int(m));
  }
}

__global__ void k_head(const float* __restrict__ gsum, const float* __restrict__ gmax,
                       const float* __restrict__ fc1w, const float* __restrict__ fc1b,
                       const float* __restrict__ fc2w, const float* __restrict__ fc2b,
                       float* __restrict__ out, int N) {
  __shared__ float g[256];
  __shared__ float red[128];
  int t = threadIdx.x;
  if (t < 128) g[t] = tanhf(gsum[t] / (float)N);
  else g[t] = tanhf(gmax[t - 128]);
  __syncthreads();
  float r1 = 0.f;
  if (t < 128) {
    float a = fc1b[t];
    for (int i = 0; i < 256; i++) a += g[i] * fc1w[i * 128 + t];
    r1 = a > 0.f ? a : 0.f;
    red[t] = r1 * fc2w[t];
  }
  __syncthreads();
  for (int s = 64; s > 0; s >>= 1) {
    if (t < s) red[t] += red[t + s];
    __syncthreads();
  }
  if (t == 0) {
    float o = red[0] + fc2b[0];
    out[0] = 1.f / (1.f + __expf(-o));
  }
}

// --------------------------------- launch ------------------------------------

extern "C" void kernel_launch(void* const* d_in, const int* in_sizes, int n_in,
                              void* d_out, int out_size, void* d_ws, size_t ws_size,
                              hipStream_t stream) {
  const float* x    = (const float*)d_in[0];
  const int*   ei   = (const int*)d_in[1];
  const int*   ety  = (const int*)d_in[2];
  const float* w0   = (const float*)d_in[3];
  const float* q0   = (const float*)d_in[4];
  const float* k0   = (const float*)d_in[5];
  const float* b0   = (const float*)d_in[6];
  const float* w1   = (const float*)d_in[7];
  const float* q1   = (const float*)d_in[8];
  const float* k1   = (const float*)d_in[9];
  const float* b1   = (const float*)d_in[10];
  const float* fc1w = (const float*)d_in[11];
  const float* fc1b = (const float*)d_in[12];
  const float* fc2w = (const float*)d_in[13];
  const float* fc2b = (const float*)d_in[14];
  int N = in_sizes[0] / 128;
  int E = in_sizes[2];
  const int* src = ei;
  const int* dst = ei + E;

  char* base = (char*)d_ws;
  size_t off = 0;
  auto alloc = [&](size_t bytes) -> void* {
    off = (off + 255) & ~(size_t)255;
    void* p = base + off;
    off += bytes;
    return p;
  };
  int*    row_ptr = (int*)alloc((size_t)(N + 1) * 4);
  int*    cursor  = (int*)alloc((size_t)N * 4);
  int*    srcs    = (int*)alloc((size_t)E * 4);
  int*    ets     = (int*)alloc((size_t)E * 4);
  int*    csums   = (int*)alloc(64 * 4);
  float*  wq      = (float*)alloc(1024 * 4);
  float*  wk      = (float*)alloc(1024 * 4);
  float*  qv      = (float*)alloc((size_t)N * 8 * 4);
  float*  kv      = (float*)alloc((size_t)N * 8 * 4);
  float*  h1      = (float*)alloc((size_t)N * 128 * 4);
  float*  h2      = (float*)alloc((size_t)N * 128 * 4);
  float*  gsum    = (float*)alloc(128 * 4);
  float*  gmax    = (float*)alloc(128 * 4);
  __bf16* xb      = (__bf16*)alloc((size_t)N * 128 * 2);
  __bf16* h1b     = (__bf16*)alloc((size_t)N * 128 * 2);
  __bf16* WT      = (__bf16*)alloc((size_t)8 * 128 * 128 * 2);
  __bf16* Y       = (__bf16*)alloc((size_t)8 * N * 128 * 2);

  // CSR build
  int nchunks = (N + SCHUNK - 1) / SCHUNK;
  hipMemsetAsync(cursor, 0, (size_t)N * 4, stream);
  k_hist<<<(E + 255) / 256, 256, 0, stream>>>(dst, cursor, E);
  k_chunk_sums<<<nchunks, 256, 0, stream>>>(cursor, csums, N);
  k_scan_sums<<<1, 64, 0, stream>>>(csums, nchunks);
  k_scan_write<<<nchunks, 256, 0, stream>>>(cursor, csums, row_ptr, N, E);
  hipMemcpyAsync(cursor, row_ptr, (size_t)N * 4, hipMemcpyDeviceToDevice, stream);
  k_scatter<<<(E + 255) / 256, 256, 0, stream>>>(src, dst, ety, cursor, srcs, ets, E);

  k_cast<<<((N * 128 / 4) + 255) / 256, 256, 0, stream>>>(x, xb, N * 128 / 4);

  for (int layer = 0; layer < 2; ++layer) {
    const float*  W    = layer ? w1 : w0;
    const float*  qq   = layer ? q1 : q0;
    const float*  kk   = layer ? k1 : k0;
    const float*  bb   = layer ? b1 : b0;
    const float*  xin  = layer ? h1 : x;     // f32 input (qv/kv)
    const __bf16* xinb = layer ? h1b : xb;   // bf16 input (transform)
    float*        hout = layer ? h2 : h1;
    __bf16*       hbout = layer ? (__bf16*)nullptr : h1b;

    k_wqk<<<8, 128, 0, stream>>>(W, qq, kk, wq, wk);
    k_qvkv<<<(N + 3) / 4, 256, 0, stream>>>(xin, wq, wk, qv, kv, N);
    {
      dim3 g(128, 8);
      k_wt<<<g, 128, 0, stream>>>(W, WT);
    }
    {
      dim3 g((N + 127) / 128, 8);
      k_gemmY<<<g, 256, 0, stream>>>(xinb, WT, Y, N);
    }
    k_agg<<<(N + 3) / 4, 256, 0, stream>>>(row_ptr, srcs, ets, qv, kv, Y, bb, hout, hbout, N);
  }

  hipMemsetAsync(gsum, 0, 128 * 4, stream);
  hipMemsetAsync(gmax, 0, 128 * 4, stream);
  k_pool<<<256, 256, 0, stream>>>(h2, gsum, gmax, N);
  k_head<<<1, 256, 0, stream>>>(gsum, gmax, fc1w, fc1b, fc2w, fc2b, (float*)d_out, N);
}

// Round 3
// 466.104 us; speedup vs baseline: 2.0093x; 1.2052x over previous
//
#include <hip/hip_runtime.h>
#include <hip/hip_bf16.h>

// ---------------------------------------------------------------------------
// RGAT: 2x RGATConv (R=8, H=128) + mean/max pool + MLP head -> scalar
//
// R3 structure (aggregate-first, cache-resident gather):
//   CSR build (by dst); xb = bf16(x)
//   per layer:
//     Wq[r]=W[r]@q, Wk[r]=W[r]@k (coalesced);  qv/kv[n,r] from bf16 feats
//     k_agg2: per node (1 wave): online-softmax over edges, lane-parallel
//             weights + readlane broadcast; acc[8] f32x2/lane; gather from
//             xb (12.8MB, L2/L3-resident); write agg[n][1024] bf16
//     k_gemm: h = relu(agg[N,1024] @ Wcat[1024,128] + b)  (bf16 MFMA, K=1024)
//   pool (mean+max, bf16 in) -> tanh -> fc1 relu -> fc2 -> sigmoid
// ---------------------------------------------------------------------------

typedef __bf16 bf16x8 __attribute__((ext_vector_type(8)));
typedef __bf16 bf16x4 __attribute__((ext_vector_type(4)));
typedef __bf16 bf16x2 __attribute__((ext_vector_type(2)));
typedef float f32x4 __attribute__((ext_vector_type(4)));

#define SCHUNK 1024

// ----------------------------- CSR build -----------------------------------

__global__ __launch_bounds__(256) void k_hist(const int* __restrict__ dst, int* __restrict__ cnt, int E) {
  int e = blockIdx.x * 256 + threadIdx.x;
  if (e < E) atomicAdd(&cnt[dst[e]], 1);
}

__global__ __launch_bounds__(256) void k_chunk_sums(const int* __restrict__ cnt, int* __restrict__ sums, int n) {
  __shared__ int sd[256];
  int base = blockIdx.x * SCHUNK;
  int t = threadIdx.x;
  int s = 0;
  for (int i = t; i < SCHUNK; i += 256) { int idx = base + i; if (idx < n) s += cnt[idx]; }
  sd[t] = s; __syncthreads();
  for (int off = 128; off; off >>= 1) { if (t < off) sd[t] += sd[t + off]; __syncthreads(); }
  if (t == 0) sums[blockIdx.x] = sd[0];
}

__global__ void k_scan_sums(int* sums, int nchunks) {
  __shared__ int sh[64];
  int t = threadIdx.x;
  sh[t] = (t < nchunks) ? sums[t] : 0;
  __syncthreads();
  if (t == 0) { int acc = 0; for (int i = 0; i < nchunks; i++) { int v = sh[i]; sh[i] = acc; acc += v; } }
  __syncthreads();
  if (t < nchunks) sums[t] = sh[t];
}

__global__ __launch_bounds__(256) void k_scan_write(const int* __restrict__ cnt, const int* __restrict__ sums,
                                                    int* __restrict__ row_ptr, int n, int total) {
  __shared__ int sd[256];
  int b = blockIdx.x, t = threadIdx.x;
  int base = b * SCHUNK + t * 4;
  int v0 = 0, v1 = 0, v2 = 0, v3 = 0;
  if (base + 0 < n) v0 = cnt[base + 0];
  if (base + 1 < n) v1 = cnt[base + 1];
  if (base + 2 < n) v2 = cnt[base + 2];
  if (base + 3 < n) v3 = cnt[base + 3];
  int s = v0 + v1 + v2 + v3;
  sd[t] = s; __syncthreads();
  for (int off = 1; off < 256; off <<= 1) {
    int x = 0; if (t >= off) x = sd[t - off];
    __syncthreads();
    sd[t] += x;
    __syncthreads();
  }
  int run = sums[b] + sd[t] - s;
  if (base + 0 < n) { row_ptr[base + 0] = run; run += v0; }
  if (base + 1 < n) { row_ptr[base + 1] = run; run += v1; }
  if (base + 2 < n) { row_ptr[base + 2] = run; run += v2; }
  if (base + 3 < n) { row_ptr[base + 3] = run; run += v3; }
  if (b == 0 && t == 0) row_ptr[n] = total;
}

__global__ __launch_bounds__(256) void k_scatter(const int* __restrict__ src, const int* __restrict__ dst,
                                                 const int* __restrict__ et, int* __restrict__ cursor,
                                                 int* __restrict__ srcs, int* __restrict__ ets, int E) {
  int e = blockIdx.x * 256 + threadIdx.x;
  if (e >= E) return;
  int d = dst[e];
  int p = atomicAdd(&cursor[d], 1);
  srcs[p] = src[e];
  ets[p] = et[e];
}

// ----------------------------- small precompute ------------------------------

// wq[r*128+i] = W[r][i][:]·q ; one wave per (r,i) row, coalesced row read.
__global__ __launch_bounds__(256) void k_wqk(const float* __restrict__ W, const float* __restrict__ q,
                                             const float* __restrict__ k, float* __restrict__ wq,
                                             float* __restrict__ wk) {
  int g = blockIdx.x * 4 + (threadIdx.x >> 6);   // row index 0..1023
  int lane = threadIdx.x & 63;
  if (g >= 1024) return;
  const float2* wrow = (const float2*)(W + (size_t)g * 128);
  float2 wv = wrow[lane];
  float2 qv2 = ((const float2*)q)[lane];
  float2 kv2 = ((const float2*)k)[lane];
  float aq = wv.x * qv2.x + wv.y * qv2.y;
  float ak = wv.x * kv2.x + wv.y * kv2.y;
  #pragma unroll
  for (int off = 32; off; off >>= 1) {
    aq += __shfl_xor(aq, off, 64);
    ak += __shfl_xor(ak, off, 64);
  }
  if (lane == 0) { wq[g] = aq; wk[g] = ak; }
}

// WT2[h][r*128+k] = bf16(W[r][k][h])   (stacked B matrix, k-contiguous rows)
__global__ __launch_bounds__(128) void k_wt(const float* __restrict__ W, __bf16* __restrict__ WT) {
  int r = blockIdx.y, h = blockIdx.x, kk = threadIdx.x;
  WT[(size_t)h * 1024 + r * 128 + kk] = (__bf16)W[((size_t)r * 128 + kk) * 128 + h];
}

__global__ __launch_bounds__(256) void k_cast(const float* __restrict__ src, __bf16* __restrict__ dst, int n4) {
  int i = blockIdx.x * 256 + threadIdx.x;
  if (i < n4) {
    float4 v = ((const float4*)src)[i];
    bf16x4 o;
    o.x = (__bf16)v.x; o.y = (__bf16)v.y; o.z = (__bf16)v.z; o.w = (__bf16)v.w;
    ((bf16x4*)dst)[i] = o;
  }
}

// qv[n][r] = x[n]·wq[r] from bf16 features. One wave per node.
__global__ __launch_bounds__(256) void k_qvkv(const __bf16* __restrict__ xin, const float* __restrict__ wq,
                                              const float* __restrict__ wk, float* __restrict__ qv,
                                              float* __restrict__ kv, int N) {
  __shared__ float swq[1024], swk[1024];
  for (int i = threadIdx.x; i < 1024; i += 256) { swq[i] = wq[i]; swk[i] = wk[i]; }
  __syncthreads();
  int lane = threadIdx.x & 63;
  int n = blockIdx.x * 4 + (threadIdx.x >> 6);
  if (n >= N) return;
  bf16x2 xv2 = ((const bf16x2*)xin)[(size_t)n * 64 + lane];
  float xx = (float)xv2.x, xy = (float)xv2.y;
  #pragma unroll
  for (int r = 0; r < 8; r++) {
    float pq = xx * swq[r * 128 + 2 * lane] + xy * swq[r * 128 + 2 * lane + 1];
    float pk = xx * swk[r * 128 + 2 * lane] + xy * swk[r * 128 + 2 * lane + 1];
    #pragma unroll
    for (int off = 32; off; off >>= 1) {
      pq += __shfl_xor(pq, off, 64);
      pk += __shfl_xor(pk, off, 64);
    }
    if (lane == 0) { qv[(size_t)n * 8 + r] = pq; kv[(size_t)n * 8 + r] = pk; }
  }
}

// ------------------- softmax + gather aggregate (to agg) ---------------------
// One wave per node. agg[n][r*128+ch] = (1/denom) * sum_{e: et=r} wgt_e * xb[src_e][ch]

__global__ __launch_bounds__(256) void k_agg2(const int* __restrict__ row_ptr, const int* __restrict__ srcs,
                                              const int* __restrict__ ets, const float* __restrict__ qv,
                                              const float* __restrict__ kv, const __bf16* __restrict__ xb,
                                              __bf16* __restrict__ agg, int N) {
  int wid = ((blockIdx.x * 256 + threadIdx.x) >> 6);
  int lane = threadIdx.x & 63;
  if (wid >= N) return;
  int n = wid;
  int start = row_ptr[n], end = row_ptr[n + 1];
  const float* qvn = qv + (size_t)n * 8;
  const bf16x2* xb2 = (const bf16x2*)xb;

  float2 acc[8];
  #pragma unroll
  for (int rr = 0; rr < 8; ++rr) acc[rr] = make_float2(0.f, 0.f);
  float denom = 0.f, m_run = -1e30f;

  for (int c0 = start; c0 < end; c0 += 64) {
    int cend = (end < c0 + 64) ? end : (c0 + 64);
    int cnt = cend - c0;
    int p = c0 + lane;
    float a = -1e30f; int s = 0, r = 0;
    if (p < cend) {
      s = srcs[p]; r = ets[p];
      float t = qvn[r] + kv[(size_t)s * 8 + r];
      a = (t >= 0.f) ? t : 0.2f * t;
    }
    float cm = a;
    #pragma unroll
    for (int off = 32; off; off >>= 1) cm = fmaxf(cm, __shfl_xor(cm, off, 64));
    if (cm > m_run) {
      float scale = __expf(m_run - cm);
      denom *= scale;
      #pragma unroll
      for (int rr = 0; rr < 8; ++rr) { acc[rr].x *= scale; acc[rr].y *= scale; }
      m_run = cm;
    }
    float wgt = (p < cend) ? __expf(a - m_run) : 0.f;
    float ws = wgt;
    #pragma unroll
    for (int off = 32; off; off >>= 1) ws += __shfl_xor(ws, off, 64);
    denom += ws;
    int wbits = __float_as_int(wgt);

#define ACC1(R, WU, XV)                                                        \
    {                                                                          \
      float fw = __int_as_float(WU);                                           \
      _Pragma("unroll")                                                        \
      for (int rr = 0; rr < 8; ++rr)                                           \
        if ((R) == rr) { acc[rr].x += fw * (float)(XV).x; acc[rr].y += fw * (float)(XV).y; } \
    }

    int e = 0;
    for (; e + 4 <= cnt; e += 4) {
      int s0 = __builtin_amdgcn_readlane(s, e + 0);
      int s1 = __builtin_amdgcn_readlane(s, e + 1);
      int s2 = __builtin_amdgcn_readlane(s, e + 2);
      int s3 = __builtin_amdgcn_readlane(s, e + 3);
      int r0 = __builtin_amdgcn_readlane(r, e + 0);
      int r1 = __builtin_amdgcn_readlane(r, e + 1);
      int r2 = __builtin_amdgcn_readlane(r, e + 2);
      int r3 = __builtin_amdgcn_readlane(r, e + 3);
      int w0 = __builtin_amdgcn_readlane(wbits, e + 0);
      int w1 = __builtin_amdgcn_readlane(wbits, e + 1);
      int w2 = __builtin_amdgcn_readlane(wbits, e + 2);
      int w3 = __builtin_amdgcn_readlane(wbits, e + 3);
      bf16x2 x0 = xb2[(size_t)s0 * 64 + lane];
      bf16x2 x1 = xb2[(size_t)s1 * 64 + lane];
      bf16x2 x2 = xb2[(size_t)s2 * 64 + lane];
      bf16x2 x3 = xb2[(size_t)s3 * 64 + lane];
      ACC1(r0, w0, x0);
      ACC1(r1, w1, x1);
      ACC1(r2, w2, x2);
      ACC1(r3, w3, x3);
    }
    for (; e < cnt; ++e) {
      int s0 = __builtin_amdgcn_readlane(s, e);
      int r0 = __builtin_amdgcn_readlane(r, e);
      int w0 = __builtin_amdgcn_readlane(wbits, e);
      bf16x2 x0 = xb2[(size_t)s0 * 64 + lane];
      ACC1(r0, w0, x0);
    }
#undef ACC1
  }

  float inv = 1.f / (denom + 1e-16f);
  bf16x2* ag2 = (bf16x2*)agg;
  size_t bptr = (size_t)n * 512;
  #pragma unroll
  for (int rr = 0; rr < 8; ++rr) {
    bf16x2 o;
    o.x = (__bf16)(acc[rr].x * inv);
    o.y = (__bf16)(acc[rr].y * inv);
    ag2[bptr + rr * 64 + lane] = o;
  }
}

// --------------------------- MFMA GEMM (K=1024) ------------------------------
// C[M,128] = relu(A[M,1024] @ B^T + bias), B given as WT2[h][k] (k-contiguous).
// Block 128x128, 4 waves, BK=64, 16 K-chunks, LDS stride 72 (2-way, free).

#define LSTR 72

__global__ __launch_bounds__(256) void k_gemm(const __bf16* __restrict__ A, const __bf16* __restrict__ B,
                                              const float* __restrict__ bias, __bf16* __restrict__ C, int M) {
  __shared__ __bf16 As[128 * LSTR];
  __shared__ __bf16 Bs[128 * LSTR];
  int bm = blockIdx.x * 128;
  int tid = threadIdx.x;
  int w = tid >> 6, l = tid & 63;

  f32x4 acc[2][8];
  #pragma unroll
  for (int m2 = 0; m2 < 2; ++m2)
    #pragma unroll
    for (int n2 = 0; n2 < 8; ++n2) acc[m2][n2] = (f32x4)0.f;

  int srow = tid >> 1;
  int cbase = (tid & 1) * 4;
  bool valid = (bm + srow) < M;

  for (int kt = 0; kt < 16; ++kt) {
    if (kt) __syncthreads();
    bf16x8 av[4], bv[4];
    const bf16x8* gA = (const bf16x8*)(A + (size_t)(bm + srow) * 1024 + kt * 64);
    const bf16x8* gB = (const bf16x8*)(B + (size_t)srow * 1024 + kt * 64);
    #pragma unroll
    for (int i = 0; i < 4; ++i) {
      av[i] = valid ? gA[cbase + i] : (bf16x8)(__bf16)0.0f;
      bv[i] = gB[cbase + i];
    }
    #pragma unroll
    for (int i = 0; i < 4; ++i) {
      *(bf16x8*)&As[srow * LSTR + (cbase + i) * 8] = av[i];
      *(bf16x8*)&Bs[srow * LSTR + (cbase + i) * 8] = bv[i];
    }
    __syncthreads();
    #pragma unroll
    for (int ks = 0; ks < 2; ++ks) {
      bf16x8 af[2], bfv[8];
      #pragma unroll
      for (int m2 = 0; m2 < 2; ++m2)
        af[m2] = *(const bf16x8*)&As[(w * 32 + m2 * 16 + (l & 15)) * LSTR + ks * 32 + (l >> 4) * 8];
      #pragma unroll
      for (int n2 = 0; n2 < 8; ++n2)
        bfv[n2] = *(const bf16x8*)&Bs[(n2 * 16 + (l & 15)) * LSTR + ks * 32 + (l >> 4) * 8];
      #pragma unroll
      for (int m2 = 0; m2 < 2; ++m2)
        #pragma unroll
        for (int n2 = 0; n2 < 8; ++n2)
          acc[m2][n2] = __builtin_amdgcn_mfma_f32_16x16x32_bf16(af[m2], bfv[n2], acc[m2][n2], 0, 0, 0);
    }
  }

  // C/D layout: col = lane&15, row = (lane>>4)*4 + reg
  #pragma unroll
  for (int m2 = 0; m2 < 2; ++m2)
    #pragma unroll
    for (int j = 0; j < 4; ++j) {
      int row = w * 32 + m2 * 16 + (l >> 4) * 4 + j;
      if (bm + row < M) {
        #pragma unroll
        for (int n2 = 0; n2 < 8; ++n2) {
          float v = acc[m2][n2][j] + bias[n2 * 16 + (l & 15)];
          v = v > 0.f ? v : 0.f;
          C[(size_t)(bm + row) * 128 + n2 * 16 + (l & 15)] = (__bf16)v;
        }
      }
    }
}

// ------------------------------- pool + head ---------------------------------

__global__ __launch_bounds__(256) void k_pool(const __bf16* __restrict__ h, float* __restrict__ gsum,
                                              float* __restrict__ gmax, int N) {
  int c2 = threadIdx.x & 63;   // channel pair index
  int grp = threadIdx.x >> 6;  // 4 node-groups per block
  float s0 = 0.f, s1 = 0.f, m0 = 0.f, m1 = 0.f;
  for (int n = blockIdx.x * 4 + grp; n < N; n += gridDim.x * 4) {
    bf16x2 v = ((const bf16x2*)(h + (size_t)n * 128))[c2];
    float v0 = (float)v.x, v1 = (float)v.y;
    s0 += v0; s1 += v1;
    m0 = fmaxf(m0, v0); m1 = fmaxf(m1, v1);
  }
  __shared__ float ss0[256], ss1[256], sm0[256], sm1[256];
  ss0[threadIdx.x] = s0; ss1[threadIdx.x] = s1;
  sm0[threadIdx.x] = m0; sm1[threadIdx.x] = m1;
  __syncthreads();
  if (grp == 0) {
    #pragma unroll
    for (int g = 1; g < 4; ++g) {
      s0 += ss0[g * 64 + c2]; s1 += ss1[g * 64 + c2];
      m0 = fmaxf(m0, sm0[g * 64 + c2]); m1 = fmaxf(m1, sm1[g * 64 + c2]);
    }
    atomicAdd(&gsum[2 * c2 + 0], s0);
    atomicAdd(&gsum[2 * c2 + 1], s1);
    atomicMax((int*)gmax + 2 * c2 + 0, __float_as_int(m0));
    atomicMax((int*)gmax + 2 * c2 + 1, __float_as_int(m1));
  }
}

__global__ void k_head(const float* __restrict__ gsum, const float* __restrict__ gmax,
                       const float* __restrict__ fc1w, const float* __restrict__ fc1b,
                       const float* __restrict__ fc2w, const float* __restrict__ fc2b,
                       float* __restrict__ out, int N) {
  __shared__ float g[256];
  __shared__ float red[128];
  int t = threadIdx.x;
  if (t < 128) g[t] = tanhf(gsum[t] / (float)N);
  else g[t] = tanhf(gmax[t - 128]);
  __syncthreads();
  float r1 = 0.f;
  if (t < 128) {
    float a = fc1b[t];
    for (int i = 0; i < 256; i++) a += g[i] * fc1w[i * 128 + t];
    r1 = a > 0.f ? a : 0.f;
    red[t] = r1 * fc2w[t];
  }
  __syncthreads();
  for (int s = 64; s > 0; s >>= 1) {
    if (t < s) red[t] += red[t + s];
    __syncthreads();
  }
  if (t == 0) {
    float o = red[0] + fc2b[0];
    out[0] = 1.f / (1.f + __expf(-o));
  }
}

// --------------------------------- launch ------------------------------------

extern "C" void kernel_launch(void* const* d_in, const int* in_sizes, int n_in,
                              void* d_out, int out_size, void* d_ws, size_t ws_size,
                              hipStream_t stream) {
  const float* x    = (const float*)d_in[0];
  const int*   ei   = (const int*)d_in[1];
  const int*   ety  = (const int*)d_in[2];
  const float* w0   = (const float*)d_in[3];
  const float* q0   = (const float*)d_in[4];
  const float* k0   = (const float*)d_in[5];
  const float* b0   = (const float*)d_in[6];
  const float* w1   = (const float*)d_in[7];
  const float* q1   = (const float*)d_in[8];
  const float* k1   = (const float*)d_in[9];
  const float* b1   = (const float*)d_in[10];
  const float* fc1w = (const float*)d_in[11];
  const float* fc1b = (const float*)d_in[12];
  const float* fc2w = (const float*)d_in[13];
  const float* fc2b = (const float*)d_in[14];
  int N = in_sizes[0] / 128;
  int E = in_sizes[2];
  const int* src = ei;
  const int* dst = ei + E;

  char* base = (char*)d_ws;
  size_t off = 0;
  auto alloc = [&](size_t bytes) -> void* {
    off = (off + 255) & ~(size_t)255;
    void* p = base + off;
    off += bytes;
    return p;
  };
  int*    row_ptr = (int*)alloc((size_t)(N + 1) * 4);
  int*    cursor  = (int*)alloc((size_t)N * 4);
  int*    srcs    = (int*)alloc((size_t)E * 4);
  int*    ets     = (int*)alloc((size_t)E * 4);
  int*    csums   = (int*)alloc(64 * 4);
  float*  wq      = (float*)alloc(1024 * 4);
  float*  wk      = (float*)alloc(1024 * 4);
  float*  qv      = (float*)alloc((size_t)N * 8 * 4);
  float*  kv      = (float*)alloc((size_t)N * 8 * 4);
  float*  gsum    = (float*)alloc(128 * 4);
  float*  gmax    = (float*)alloc(128 * 4);
  __bf16* xb      = (__bf16*)alloc((size_t)N * 128 * 2);
  __bf16* h1b     = (__bf16*)alloc((size_t)N * 128 * 2);
  __bf16* h2b     = (__bf16*)alloc((size_t)N * 128 * 2);
  __bf16* WT2     = (__bf16*)alloc((size_t)128 * 1024 * 2);
  __bf16* agg     = (__bf16*)alloc((size_t)N * 1024 * 2);

  // CSR build
  int nchunks = (N + SCHUNK - 1) / SCHUNK;
  hipMemsetAsync(cursor, 0, (size_t)N * 4, stream);
  k_hist<<<(E + 255) / 256, 256, 0, stream>>>(dst, cursor, E);
  k_chunk_sums<<<nchunks, 256, 0, stream>>>(cursor, csums, N);
  k_scan_sums<<<1, 64, 0, stream>>>(csums, nchunks);
  k_scan_write<<<nchunks, 256, 0, stream>>>(cursor, csums, row_ptr, N, E);
  hipMemcpyAsync(cursor, row_ptr, (size_t)N * 4, hipMemcpyDeviceToDevice, stream);
  k_scatter<<<(E + 255) / 256, 256, 0, stream>>>(src, dst, ety, cursor, srcs, ets, E);

  k_cast<<<((N * 32) + 255) / 256, 256, 0, stream>>>(x, xb, N * 32);

  for (int layer = 0; layer < 2; ++layer) {
    const float*  W    = layer ? w1 : w0;
    const float*  qq   = layer ? q1 : q0;
    const float*  kk   = layer ? k1 : k0;
    const float*  bb   = layer ? b1 : b0;
    const __bf16* xinb = layer ? h1b : xb;
    __bf16*       hout = layer ? h2b : h1b;

    k_wqk<<<256, 256, 0, stream>>>(W, qq, kk, wq, wk);
    k_qvkv<<<(N + 3) / 4, 256, 0, stream>>>(xinb, wq, wk, qv, kv, N);
    {
      dim3 g(128, 8);
      k_wt<<<g, 128, 0, stream>>>(W, WT2);
    }
    k_agg2<<<(N + 3) / 4, 256, 0, stream>>>(row_ptr, srcs, ets, qv, kv, xinb, agg, N);
    k_gemm<<<(N + 127) / 128, 256, 0, stream>>>(agg, WT2, bb, hout, N);
  }

  hipMemsetAsync(gsum, 0, 128 * 4, stream);
  hipMemsetAsync(gmax, 0, 128 * 4, stream);
  k_pool<<<256, 256, 0, stream>>>(h2b, gsum, gmax, N);
  k_head<<<1, 256, 0, stream>>>(gsum, gmax, fc1w, fc1b, fc2w, fc2b, (float*)d_out, N);
}

// Round 4
// 442.477 us; speedup vs baseline: 2.1166x; 1.0534x over previous
//
#include <hip/hip_runtime.h>
#include <hip/hip_bf16.h>

// ---------------------------------------------------------------------------
// RGAT: 2x RGATConv (R=8, H=128) + mean/max pool + MLP head -> scalar
//
// R4 structure (aggregate-first; LDS accumulator kills the 8-way select):
//   CSR build (by dst); xb = bf16(x)
//   per layer:
//     Wq[r]=W[r]@q, Wk[r]=W[r]@k; qv/kv[n,r] from bf16 feats
//     k_agg2: 1 wave/node; online-softmax weights lane-parallel (64-edge
//             chunks); serial accumulate via LDS row acc[1024] f32 --
//             relation index is ADDRESS MATH, not a predicate chain.
//     k_gemm: h = relu(agg[N,1024] @ Wcat[1024,128] + b), bf16 MFMA,
//             reg-prefetch of next K-tile under MFMA.
//   pool (mean+max) -> tanh -> fc1 relu -> fc2 -> sigmoid
// ---------------------------------------------------------------------------

typedef __bf16 bf16x8 __attribute__((ext_vector_type(8)));
typedef __bf16 bf16x4 __attribute__((ext_vector_type(4)));
typedef __bf16 bf16x2 __attribute__((ext_vector_type(2)));
typedef float f32x4 __attribute__((ext_vector_type(4)));

#define SCHUNK 1024

// ----------------------------- CSR build -----------------------------------

__global__ __launch_bounds__(256) void k_hist(const int* __restrict__ dst, int* __restrict__ cnt, int E) {
  int e = blockIdx.x * 256 + threadIdx.x;
  if (e < E) atomicAdd(&cnt[dst[e]], 1);
}

__global__ __launch_bounds__(256) void k_chunk_sums(const int* __restrict__ cnt, int* __restrict__ sums, int n) {
  __shared__ int sd[256];
  int base = blockIdx.x * SCHUNK;
  int t = threadIdx.x;
  int s = 0;
  for (int i = t; i < SCHUNK; i += 256) { int idx = base + i; if (idx < n) s += cnt[idx]; }
  sd[t] = s; __syncthreads();
  for (int off = 128; off; off >>= 1) { if (t < off) sd[t] += sd[t + off]; __syncthreads(); }
  if (t == 0) sums[blockIdx.x] = sd[0];
}

__global__ void k_scan_sums(int* sums, int nchunks) {
  __shared__ int sh[64];
  int t = threadIdx.x;
  sh[t] = (t < nchunks) ? sums[t] : 0;
  __syncthreads();
  if (t == 0) { int acc = 0; for (int i = 0; i < nchunks; i++) { int v = sh[i]; sh[i] = acc; acc += v; } }
  __syncthreads();
  if (t < nchunks) sums[t] = sh[t];
}

__global__ __launch_bounds__(256) void k_scan_write(const int* __restrict__ cnt, const int* __restrict__ sums,
                                                    int* __restrict__ row_ptr, int n, int total) {
  __shared__ int sd[256];
  int b = blockIdx.x, t = threadIdx.x;
  int base = b * SCHUNK + t * 4;
  int v0 = 0, v1 = 0, v2 = 0, v3 = 0;
  if (base + 0 < n) v0 = cnt[base + 0];
  if (base + 1 < n) v1 = cnt[base + 1];
  if (base + 2 < n) v2 = cnt[base + 2];
  if (base + 3 < n) v3 = cnt[base + 3];
  int s = v0 + v1 + v2 + v3;
  sd[t] = s; __syncthreads();
  for (int off = 1; off < 256; off <<= 1) {
    int x = 0; if (t >= off) x = sd[t - off];
    __syncthreads();
    sd[t] += x;
    __syncthreads();
  }
  int run = sums[b] + sd[t] - s;
  if (base + 0 < n) { row_ptr[base + 0] = run; run += v0; }
  if (base + 1 < n) { row_ptr[base + 1] = run; run += v1; }
  if (base + 2 < n) { row_ptr[base + 2] = run; run += v2; }
  if (base + 3 < n) { row_ptr[base + 3] = run; run += v3; }
  if (b == 0 && t == 0) row_ptr[n] = total;
}

__global__ __launch_bounds__(256) void k_scatter(const int* __restrict__ src, const int* __restrict__ dst,
                                                 const int* __restrict__ et, int* __restrict__ cursor,
                                                 int* __restrict__ srcs, int* __restrict__ ets, int E) {
  int e = blockIdx.x * 256 + threadIdx.x;
  if (e >= E) return;
  int d = dst[e];
  int p = atomicAdd(&cursor[d], 1);
  srcs[p] = src[e];
  ets[p] = et[e];
}

// ----------------------------- small precompute ------------------------------

// wq[r*128+i] = W[r][i][:]·q ; one wave per row, coalesced.
__global__ __launch_bounds__(256) void k_wqk(const float* __restrict__ W, const float* __restrict__ q,
                                             const float* __restrict__ k, float* __restrict__ wq,
                                             float* __restrict__ wk) {
  int g = blockIdx.x * 4 + (threadIdx.x >> 6);
  int lane = threadIdx.x & 63;
  if (g >= 1024) return;
  const float2* wrow = (const float2*)(W + (size_t)g * 128);
  float2 wv = wrow[lane];
  float2 qv2 = ((const float2*)q)[lane];
  float2 kv2 = ((const float2*)k)[lane];
  float aq = wv.x * qv2.x + wv.y * qv2.y;
  float ak = wv.x * kv2.x + wv.y * kv2.y;
  #pragma unroll
  for (int off = 32; off; off >>= 1) {
    aq += __shfl_xor(aq, off, 64);
    ak += __shfl_xor(ak, off, 64);
  }
  if (lane == 0) { wq[g] = aq; wk[g] = ak; }
}

// WT2[h][r*128+k] = bf16(W[r][k][h]) via LDS 32x32 tile transpose (coalesced both sides).
__global__ __launch_bounds__(256) void k_wt(const float* __restrict__ W, __bf16* __restrict__ WT) {
  __shared__ float t[32][33];
  int r = blockIdx.z;
  int k0 = blockIdx.x * 32, h0 = blockIdx.y * 32;
  int tx = threadIdx.x & 31;
  int ty = threadIdx.x >> 5;    // 0..7
  #pragma unroll
  for (int i = 0; i < 4; ++i) {
    int kk = ty + i * 8;
    t[kk][tx] = W[((size_t)r * 128 + k0 + kk) * 128 + h0 + tx];
  }
  __syncthreads();
  #pragma unroll
  for (int i = 0; i < 4; ++i) {
    int hh = ty + i * 8;
    WT[(size_t)(h0 + hh) * 1024 + r * 128 + k0 + tx] = (__bf16)t[tx][hh];
  }
}

__global__ __launch_bounds__(256) void k_cast(const float* __restrict__ src, __bf16* __restrict__ dst, int n4) {
  int i = blockIdx.x * 256 + threadIdx.x;
  if (i < n4) {
    float4 v = ((const float4*)src)[i];
    bf16x4 o;
    o.x = (__bf16)v.x; o.y = (__bf16)v.y; o.z = (__bf16)v.z; o.w = (__bf16)v.w;
    ((bf16x4*)dst)[i] = o;
  }
}

// qv[n][r] = x[n]·wq[r] from bf16 features. One wave per node.
__global__ __launch_bounds__(256) void k_qvkv(const __bf16* __restrict__ xin, const float* __restrict__ wq,
                                              const float* __restrict__ wk, float* __restrict__ qv,
                                              float* __restrict__ kv, int N) {
  __shared__ float swq[1024], swk[1024];
  for (int i = threadIdx.x; i < 1024; i += 256) { swq[i] = wq[i]; swk[i] = wk[i]; }
  __syncthreads();
  int lane = threadIdx.x & 63;
  int n = blockIdx.x * 4 + (threadIdx.x >> 6);
  if (n >= N) return;
  bf16x2 xv2 = ((const bf16x2*)xin)[(size_t)n * 64 + lane];
  float xx = (float)xv2.x, xy = (float)xv2.y;
  #pragma unroll
  for (int r = 0; r < 8; r++) {
    float pq = xx * swq[r * 128 + 2 * lane] + xy * swq[r * 128 + 2 * lane + 1];
    float pk = xx * swk[r * 128 + 2 * lane] + xy * swk[r * 128 + 2 * lane + 1];
    #pragma unroll
    for (int off = 32; off; off >>= 1) {
      pq += __shfl_xor(pq, off, 64);
      pk += __shfl_xor(pk, off, 64);
    }
    if (lane == 0) { qv[(size_t)n * 8 + r] = pq; kv[(size_t)n * 8 + r] = pk; }
  }
}

// ------------------- softmax + gather aggregate (to agg) ---------------------
// One wave per node; LDS row accumulator [1024] f32 per wave.
// agg[n][r*128+ch] = (1/denom) * sum_{e: et=r} wgt_e * xb[src_e][ch]

__global__ __launch_bounds__(256) void k_agg2(const int* __restrict__ row_ptr, const int* __restrict__ srcs,
                                              const int* __restrict__ ets, const float* __restrict__ qv,
                                              const float* __restrict__ kv, const __bf16* __restrict__ xb,
                                              __bf16* __restrict__ agg, int N) {
  __shared__ float lacc[4][1024];
  int wv = threadIdx.x >> 6;
  int lane = threadIdx.x & 63;
  int n = blockIdx.x * 4 + wv;
  if (n >= N) return;
  float* A = lacc[wv];                 // private per-wave region; LDS is in-order per wave
  #pragma unroll
  for (int i = 0; i < 8; ++i)
    *(float2*)&A[i * 128 + 2 * lane] = make_float2(0.f, 0.f);

  int start = row_ptr[n], end = row_ptr[n + 1];
  const float* qvn = qv + (size_t)n * 8;
  const bf16x2* xb2 = (const bf16x2*)xb;
  float denom = 0.f, m_run = -1e30f;

  for (int c0 = start; c0 < end; c0 += 64) {
    int cend = (end < c0 + 64) ? end : (c0 + 64);
    int cnt = cend - c0;
    int p = c0 + lane;
    float a = -1e30f; int s = 0, r = 0;
    if (p < cend) {
      s = srcs[p]; r = ets[p];
      float t = qvn[r] + kv[(size_t)s * 8 + r];
      a = (t >= 0.f) ? t : 0.2f * t;
    }
    float cm = a;
    #pragma unroll
    for (int off = 32; off; off >>= 1) cm = fmaxf(cm, __shfl_xor(cm, off, 64));
    if (cm > m_run) {
      if (m_run > -1e29f) {            // only rescale if something accumulated
        float scale = __expf(m_run - cm);
        denom *= scale;
        #pragma unroll
        for (int i = 0; i < 8; ++i) {
          float2 c = *(float2*)&A[i * 128 + 2 * lane];
          c.x *= scale; c.y *= scale;
          *(float2*)&A[i * 128 + 2 * lane] = c;
        }
      }
      m_run = cm;
    }
    float wgt = (p < cend) ? __expf(a - m_run) : 0.f;
    float ws = wgt;
    #pragma unroll
    for (int off = 32; off; off >>= 1) ws += __shfl_xor(ws, off, 64);
    denom += ws;
    int wbits = __float_as_int(wgt);

#define RMW(SS, RR, WW, XV)                                                    \
    {                                                                          \
      float fw = __int_as_float(WW);                                           \
      float* ap = &A[(RR) * 128 + 2 * lane];                                   \
      float2 c = *(float2*)ap;                                                 \
      c.x += fw * (float)(XV).x;                                               \
      c.y += fw * (float)(XV).y;                                               \
      *(float2*)ap = c;                                                        \
    }

    int e = 0;
    for (; e + 4 <= cnt; e += 4) {
      int s0 = __builtin_amdgcn_readlane(s, e + 0);
      int s1 = __builtin_amdgcn_readlane(s, e + 1);
      int s2 = __builtin_amdgcn_readlane(s, e + 2);
      int s3 = __builtin_amdgcn_readlane(s, e + 3);
      int r0 = __builtin_amdgcn_readlane(r, e + 0);
      int r1 = __builtin_amdgcn_readlane(r, e + 1);
      int r2 = __builtin_amdgcn_readlane(r, e + 2);
      int r3 = __builtin_amdgcn_readlane(r, e + 3);
      int w0 = __builtin_amdgcn_readlane(wbits, e + 0);
      int w1 = __builtin_amdgcn_readlane(wbits, e + 1);
      int w2 = __builtin_amdgcn_readlane(wbits, e + 2);
      int w3 = __builtin_amdgcn_readlane(wbits, e + 3);
      bf16x2 x0 = xb2[(size_t)s0 * 64 + lane];
      bf16x2 x1 = xb2[(size_t)s1 * 64 + lane];
      bf16x2 x2 = xb2[(size_t)s2 * 64 + lane];
      bf16x2 x3 = xb2[(size_t)s3 * 64 + lane];
      RMW(s0, r0, w0, x0);
      RMW(s1, r1, w1, x1);
      RMW(s2, r2, w2, x2);
      RMW(s3, r3, w3, x3);
    }
    for (; e < cnt; ++e) {
      int s0 = __builtin_amdgcn_readlane(s, e);
      int r0 = __builtin_amdgcn_readlane(r, e);
      int w0 = __builtin_amdgcn_readlane(wbits, e);
      bf16x2 x0 = xb2[(size_t)s0 * 64 + lane];
      RMW(s0, r0, w0, x0);
    }
#undef RMW
  }

  float inv = 1.f / (denom + 1e-16f);
  bf16x2* ag2 = (bf16x2*)agg;
  size_t bptr = (size_t)n * 512;
  #pragma unroll
  for (int i = 0; i < 8; ++i) {
    float2 c = *(float2*)&A[i * 128 + 2 * lane];
    bf16x2 o;
    o.x = (__bf16)(c.x * inv);
    o.y = (__bf16)(c.y * inv);
    ag2[bptr + i * 64 + lane] = o;
  }
}

// --------------------------- MFMA GEMM (K=1024) ------------------------------
// C[M,128] = relu(A[M,1024] @ B^T + bias), B as WT2[h][k] (k-contiguous).
// Block 128x128, 4 waves, BK=64, reg-prefetch of next tile under MFMA.

#define LSTR 72

__global__ __launch_bounds__(256) void k_gemm(const __bf16* __restrict__ A, const __bf16* __restrict__ B,
                                              const float* __restrict__ bias, __bf16* __restrict__ C, int M) {
  __shared__ __bf16 As[128 * LSTR];
  __shared__ __bf16 Bs[128 * LSTR];
  int bm = blockIdx.x * 128;
  int tid = threadIdx.x;
  int w = tid >> 6, l = tid & 63;

  f32x4 acc[2][8];
  #pragma unroll
  for (int m2 = 0; m2 < 2; ++m2)
    #pragma unroll
    for (int n2 = 0; n2 < 8; ++n2) acc[m2][n2] = (f32x4)0.f;

  int srow = tid >> 1;
  int cbase = (tid & 1) * 4;
  bool valid = (bm + srow) < M;
  const bf16x8* gA = (const bf16x8*)(A + (size_t)(bm + srow) * 1024);
  const bf16x8* gB = (const bf16x8*)(B + (size_t)srow * 1024);

  bf16x8 av[4], bv[4];
  #pragma unroll
  for (int i = 0; i < 4; ++i) {
    av[i] = valid ? gA[cbase + i] : (bf16x8)(__bf16)0.0f;
    bv[i] = gB[cbase + i];
  }

  for (int kt = 0; kt < 16; ++kt) {
    if (kt) __syncthreads();
    #pragma unroll
    for (int i = 0; i < 4; ++i) {
      *(bf16x8*)&As[srow * LSTR + (cbase + i) * 8] = av[i];
      *(bf16x8*)&Bs[srow * LSTR + (cbase + i) * 8] = bv[i];
    }
    __syncthreads();
    if (kt < 15) {
      #pragma unroll
      for (int i = 0; i < 4; ++i) {
        av[i] = valid ? gA[(kt + 1) * 8 + cbase + i] : (bf16x8)(__bf16)0.0f;
        bv[i] = gB[(kt + 1) * 8 + cbase + i];
      }
    }
    #pragma unroll
    for (int ks = 0; ks < 2; ++ks) {
      bf16x8 af[2], bfv[8];
      #pragma unroll
      for (int m2 = 0; m2 < 2; ++m2)
        af[m2] = *(const bf16x8*)&As[(w * 32 + m2 * 16 + (l & 15)) * LSTR + ks * 32 + (l >> 4) * 8];
      #pragma unroll
      for (int n2 = 0; n2 < 8; ++n2)
        bfv[n2] = *(const bf16x8*)&Bs[(n2 * 16 + (l & 15)) * LSTR + ks * 32 + (l >> 4) * 8];
      #pragma unroll
      for (int m2 = 0; m2 < 2; ++m2)
        #pragma unroll
        for (int n2 = 0; n2 < 8; ++n2)
          acc[m2][n2] = __builtin_amdgcn_mfma_f32_16x16x32_bf16(af[m2], bfv[n2], acc[m2][n2], 0, 0, 0);
    }
  }

  // C/D layout: col = lane&15, row = (lane>>4)*4 + reg
  #pragma unroll
  for (int m2 = 0; m2 < 2; ++m2)
    #pragma unroll
    for (int j = 0; j < 4; ++j) {
      int row = w * 32 + m2 * 16 + (l >> 4) * 4 + j;
      if (bm + row < M) {
        #pragma unroll
        for (int n2 = 0; n2 < 8; ++n2) {
          float v = acc[m2][n2][j] + bias[n2 * 16 + (l & 15)];
          v = v > 0.f ? v : 0.f;
          C[(size_t)(bm + row) * 128 + n2 * 16 + (l & 15)] = (__bf16)v;
        }
      }
    }
}

// ------------------------------- pool + head ---------------------------------

__global__ __launch_bounds__(256) void k_pool(const __bf16* __restrict__ h, float* __restrict__ gsum,
                                              float* __restrict__ gmax, int N) {
  int c2 = threadIdx.x & 63;
  int grp = threadIdx.x >> 6;
  float s0 = 0.f, s1 = 0.f, m0 = 0.f, m1 = 0.f;
  for (int n = blockIdx.x * 4 + grp; n < N; n += gridDim.x * 4) {
    bf16x2 v = ((const bf16x2*)(h + (size_t)n * 128))[c2];
    float v0 = (float)v.x, v1 = (float)v.y;
    s0 += v0; s1 += v1;
    m0 = fmaxf(m0, v0); m1 = fmaxf(m1, v1);
  }
  __shared__ float ss0[256], ss1[256], sm0[256], sm1[256];
  ss0[threadIdx.x] = s0; ss1[threadIdx.x] = s1;
  sm0[threadIdx.x] = m0; sm1[threadIdx.x] = m1;
  __syncthreads();
  if (grp == 0) {
    #pragma unroll
    for (int g = 1; g < 4; ++g) {
      s0 += ss0[g * 64 + c2]; s1 += ss1[g * 64 + c2];
      m0 = fmaxf(m0, sm0[g * 64 + c2]); m1 = fmaxf(m1, sm1[g * 64 + c2]);
    }
    atomicAdd(&gsum[2 * c2 + 0], s0);
    atomicAdd(&gsum[2 * c2 + 1], s1);
    atomicMax((int*)gmax + 2 * c2 + 0, __float_as_int(m0));
    atomicMax((int*)gmax + 2 * c2 + 1, __float_as_int(m1));
  }
}

__global__ void k_head(const float* __restrict__ gsum, const float* __restrict__ gmax,
                       const float* __restrict__ fc1w, const float* __restrict__ fc1b,
                       const float* __restrict__ fc2w, const float* __restrict__ fc2b,
                       float* __restrict__ out, int N) {
  __shared__ float g[256];
  __shared__ float red[128];
  int t = threadIdx.x;
  if (t < 128) g[t] = tanhf(gsum[t] / (float)N);
  else g[t] = tanhf(gmax[t - 128]);
  __syncthreads();
  float r1 = 0.f;
  if (t < 128) {
    float a = fc1b[t];
    for (int i = 0; i < 256; i++) a += g[i] * fc1w[i * 128 + t];
    r1 = a > 0.f ? a : 0.f;
    red[t] = r1 * fc2w[t];
  }
  __syncthreads();
  for (int s = 64; s > 0; s >>= 1) {
    if (t < s) red[t] += red[t + s];
    __syncthreads();
  }
  if (t == 0) {
    float o = red[0] + fc2b[0];
    out[0] = 1.f / (1.f + __expf(-o));
  }
}

// --------------------------------- launch ------------------------------------

extern "C" void kernel_launch(void* const* d_in, const int* in_sizes, int n_in,
                              void* d_out, int out_size, void* d_ws, size_t ws_size,
                              hipStream_t stream) {
  const float* x    = (const float*)d_in[0];
  const int*   ei   = (const int*)d_in[1];
  const int*   ety  = (const int*)d_in[2];
  const float* w0   = (const float*)d_in[3];
  const float* q0   = (const float*)d_in[4];
  const float* k0   = (const float*)d_in[5];
  const float* b0   = (const float*)d_in[6];
  const float* w1   = (const float*)d_in[7];
  const float* q1   = (const float*)d_in[8];
  const float* k1   = (const float*)d_in[9];
  const float* b1   = (const float*)d_in[10];
  const float* fc1w = (const float*)d_in[11];
  const float* fc1b = (const float*)d_in[12];
  const float* fc2w = (const float*)d_in[13];
  const float* fc2b = (const float*)d_in[14];
  int N = in_sizes[0] / 128;
  int E = in_sizes[2];
  const int* src = ei;
  const int* dst = ei + E;

  char* base = (char*)d_ws;
  size_t off = 0;
  auto alloc = [&](size_t bytes) -> void* {
    off = (off + 255) & ~(size_t)255;
    void* p = base + off;
    off += bytes;
    return p;
  };
  int*    row_ptr = (int*)alloc((size_t)(N + 1) * 4);
  int*    cursor  = (int*)alloc((size_t)N * 4);
  int*    srcs    = (int*)alloc((size_t)E * 4);
  int*    ets     = (int*)alloc((size_t)E * 4);
  int*    csums   = (int*)alloc(64 * 4);
  float*  wq      = (float*)alloc(1024 * 4);
  float*  wk      = (float*)alloc(1024 * 4);
  float*  qv      = (float*)alloc((size_t)N * 8 * 4);
  float*  kv      = (float*)alloc((size_t)N * 8 * 4);
  float*  gsum    = (float*)alloc(128 * 4);
  float*  gmax    = (float*)alloc(128 * 4);
  __bf16* xb      = (__bf16*)alloc((size_t)N * 128 * 2);
  __bf16* h1b     = (__bf16*)alloc((size_t)N * 128 * 2);
  __bf16* h2b     = (__bf16*)alloc((size_t)N * 128 * 2);
  __bf16* WT2     = (__bf16*)alloc((size_t)128 * 1024 * 2);
  __bf16* agg     = (__bf16*)alloc((size_t)N * 1024 * 2);

  // CSR build
  int nchunks = (N + SCHUNK - 1) / SCHUNK;
  hipMemsetAsync(cursor, 0, (size_t)N * 4, stream);
  k_hist<<<(E + 255) / 256, 256, 0, stream>>>(dst, cursor, E);
  k_chunk_sums<<<nchunks, 256, 0, stream>>>(cursor, csums, N);
  k_scan_sums<<<1, 64, 0, stream>>>(csums, nchunks);
  k_scan_write<<<nchunks, 256, 0, stream>>>(cursor, csums, row_ptr, N, E);
  hipMemcpyAsync(cursor, row_ptr, (size_t)N * 4, hipMemcpyDeviceToDevice, stream);
  k_scatter<<<(E + 255) / 256, 256, 0, stream>>>(src, dst, ety, cursor, srcs, ets, E);

  k_cast<<<((N * 32) + 255) / 256, 256, 0, stream>>>(x, xb, N * 32);

  for (int layer = 0; layer < 2; ++layer) {
    const float*  W    = layer ? w1 : w0;
    const float*  qq   = layer ? q1 : q0;
    const float*  kk   = layer ? k1 : k0;
    const float*  bb   = layer ? b1 : b0;
    const __bf16* xinb = layer ? h1b : xb;
    __bf16*       hout = layer ? h2b : h1b;

    k_wqk<<<256, 256, 0, stream>>>(W, qq, kk, wq, wk);
    k_qvkv<<<(N + 3) / 4, 256, 0, stream>>>(xinb, wq, wk, qv, kv, N);
    {
      dim3 g(4, 4, 8);
      k_wt<<<g, 256, 0, stream>>>(W, WT2);
    }
    k_agg2<<<(N + 3) / 4, 256, 0, stream>>>(row_ptr, srcs, ets, qv, kv, xinb, agg, N);
    k_gemm<<<(N + 127) / 128, 256, 0, stream>>>(agg, WT2, bb, hout, N);
  }

  hipMemsetAsync(gsum, 0, 128 * 4, stream);
  hipMemsetAsync(gmax, 0, 128 * 4, stream);
  k_pool<<<256, 256, 0, stream>>>(h2b, gsum, gmax, N);
  k_head<<<1, 256, 0, stream>>>(gsum, gmax, fc1w, fc1b, fc2w, fc2b, (float*)d_out, N);
}

// Round 5
// 363.820 us; speedup vs baseline: 2.5742x; 1.2162x over previous
//
#include <hip/hip_runtime.h>
#include <hip/hip_bf16.h>

// ---------------------------------------------------------------------------
// RGAT: 2x RGATConv (R=8, H=128) + mean/max pool + MLP head -> scalar
//
// R5 structure:
//   CSR build: hist -> scan -> two-pass binned scatter (packed 4B records,
//              LDS-cursor bucket sort; kills random-write amplification)
//   xb = bf16(x)
//   per layer:
//     k_wqk:  wqkb[16][128] = bf16(concat(W[r]@q, W[r]@k))
//     k_qkv:  qkv[N][16] = xb @ wqkb^T        (MFMA 16x16x32, wave per 16 nodes)
//     k_agg2: 1 wave/node; online-softmax lane-parallel; serial accumulate
//             into LDS row acc[1024] (relation = address math)
//     k_gemm: h = relu(agg[N,1024] @ Wcat[1024,128] + b)  (bf16 MFMA)
//   pool (mean+max) -> tanh -> fc1 relu -> fc2 -> sigmoid
//
// Packing: rec = src | et<<21 | dlow<<24  (src < 2^21; N=50000 fits)
// ---------------------------------------------------------------------------

typedef __bf16 bf16x8 __attribute__((ext_vector_type(8)));
typedef __bf16 bf16x4 __attribute__((ext_vector_type(4)));
typedef __bf16 bf16x2 __attribute__((ext_vector_type(2)));
typedef float f32x4 __attribute__((ext_vector_type(4)));

#define SCHUNK 1024
#define BSH 4                    // bucket = 16 nodes

// ----------------------------- CSR build -----------------------------------

__global__ __launch_bounds__(256) void k_hist(const int* __restrict__ dst, int* __restrict__ cnt, int E) {
  int e = blockIdx.x * 256 + threadIdx.x;
  if (e < E) atomicAdd(&cnt[dst[e]], 1);
}

__global__ __launch_bounds__(256) void k_chunk_sums(const int* __restrict__ cnt, int* __restrict__ sums, int n) {
  __shared__ int sd[256];
  int base = blockIdx.x * SCHUNK;
  int t = threadIdx.x;
  int s = 0;
  for (int i = t; i < SCHUNK; i += 256) { int idx = base + i; if (idx < n) s += cnt[idx]; }
  sd[t] = s; __syncthreads();
  for (int off = 128; off; off >>= 1) { if (t < off) sd[t] += sd[t + off]; __syncthreads(); }
  if (t == 0) sums[blockIdx.x] = sd[0];
}

__global__ void k_scan_sums(int* sums, int nchunks) {
  __shared__ int sh[64];
  int t = threadIdx.x;
  sh[t] = (t < nchunks) ? sums[t] : 0;
  __syncthreads();
  if (t == 0) { int acc = 0; for (int i = 0; i < nchunks; i++) { int v = sh[i]; sh[i] = acc; acc += v; } }
  __syncthreads();
  if (t < nchunks) sums[t] = sh[t];
}

__global__ __launch_bounds__(256) void k_scan_write(const int* __restrict__ cnt, const int* __restrict__ sums,
                                                    int* __restrict__ row_ptr, int n, int total) {
  __shared__ int sd[256];
  int b = blockIdx.x, t = threadIdx.x;
  int base = b * SCHUNK + t * 4;
  int v0 = 0, v1 = 0, v2 = 0, v3 = 0;
  if (base + 0 < n) v0 = cnt[base + 0];
  if (base + 1 < n) v1 = cnt[base + 1];
  if (base + 2 < n) v2 = cnt[base + 2];
  if (base + 3 < n) v3 = cnt[base + 3];
  int s = v0 + v1 + v2 + v3;
  sd[t] = s; __syncthreads();
  for (int off = 1; off < 256; off <<= 1) {
    int x = 0; if (t >= off) x = sd[t - off];
    __syncthreads();
    sd[t] += x;
    __syncthreads();
  }
  int run = sums[b] + sd[t] - s;
  if (base + 0 < n) { row_ptr[base + 0] = run; run += v0; }
  if (base + 1 < n) { row_ptr[base + 1] = run; run += v1; }
  if (base + 2 < n) { row_ptr[base + 2] = run; run += v2; }
  if (base + 3 < n) { row_ptr[base + 3] = run; run += v3; }
  if (b == 0 && t == 0) row_ptr[n] = total;
}

// bcur[b] = row_ptr[min(b*16, N)]
__global__ __launch_bounds__(256) void k_binit(const int* __restrict__ row_ptr, int* __restrict__ bcur,
                                               int nb, int N) {
  int b = blockIdx.x * 256 + threadIdx.x;
  if (b < nb) {
    int d0 = b << BSH;
    bcur[b] = row_ptr[d0 < N ? d0 : N];
  }
}

// bin edges by dst>>4; bucket regions fill sequentially (L2-coalesced writes)
__global__ __launch_bounds__(256) void k_binscatter(const int* __restrict__ src, const int* __restrict__ dst,
                                                    const int* __restrict__ et, int* __restrict__ bcur,
                                                    int* __restrict__ tmp, int E) {
  int e = blockIdx.x * 256 + threadIdx.x;
  if (e >= E) return;
  int d = dst[e];
  int p = atomicAdd(&bcur[d >> BSH], 1);
  tmp[p] = src[e] | (et[e] << 21) | ((d & ((1 << BSH) - 1)) << 24);
}

// per-bucket final sort via LDS cursors (buckets partition nodes -> no global atomics)
__global__ __launch_bounds__(256) void k_binsort(const int* __restrict__ row_ptr, const int* __restrict__ tmp,
                                                 int* __restrict__ recs, int N, int E) {
  __shared__ int cur[1 << BSH];
  int b = blockIdx.x;
  int d0 = b << BSH;
  int t = threadIdx.x;
  if (t < (1 << BSH)) {
    int d = d0 + t;
    cur[t] = (d < N) ? row_ptr[d] : E;
  }
  int begin = row_ptr[d0 < N ? d0 : N];
  int endd = ((d0 + (1 << BSH)) < N) ? row_ptr[d0 + (1 << BSH)] : E;
  __syncthreads();
  for (int i = begin + t; i < endd; i += 256) {
    int rc = tmp[i];
    int dlow = (rc >> 24) & ((1 << BSH) - 1);
    int p = atomicAdd(&cur[dlow], 1);
    recs[p] = rc & 0xFFFFFF;     // src | et<<21
  }
}

// ----------------------------- small precompute ------------------------------

// wqkb[c][i], c<8: W[c][i][:]·q ; c>=8: W[c-8][i][:]·k.  One wave per (r,i) row.
__global__ __launch_bounds__(256) void k_wqk(const float* __restrict__ W, const float* __restrict__ q,
                                             const float* __restrict__ k, __bf16* __restrict__ wqkb) {
  int g = blockIdx.x * 4 + (threadIdx.x >> 6);
  int lane = threadIdx.x & 63;
  if (g >= 1024) return;
  const float2* wrow = (const float2*)(W + (size_t)g * 128);
  float2 wv = wrow[lane];
  float2 qv2 = ((const float2*)q)[lane];
  float2 kv2 = ((const float2*)k)[lane];
  float aq = wv.x * qv2.x + wv.y * qv2.y;
  float ak = wv.x * kv2.x + wv.y * kv2.y;
  #pragma unroll
  for (int off = 32; off; off >>= 1) {
    aq += __shfl_xor(aq, off, 64);
    ak += __shfl_xor(ak, off, 64);
  }
  if (lane == 0) { wqkb[g] = (__bf16)aq; wqkb[1024 + g] = (__bf16)ak; }
}

// WT2[h][r*128+k] = bf16(W[r][k][h]) via LDS 32x32 tile transpose.
__global__ __launch_bounds__(256) void k_wt(const float* __restrict__ W, __bf16* __restrict__ WT) {
  __shared__ float t[32][33];
  int r = blockIdx.z;
  int k0 = blockIdx.x * 32, h0 = blockIdx.y * 32;
  int tx = threadIdx.x & 31;
  int ty = threadIdx.x >> 5;
  #pragma unroll
  for (int i = 0; i < 4; ++i) {
    int kk = ty + i * 8;
    t[kk][tx] = W[((size_t)r * 128 + k0 + kk) * 128 + h0 + tx];
  }
  __syncthreads();
  #pragma unroll
  for (int i = 0; i < 4; ++i) {
    int hh = ty + i * 8;
    WT[(size_t)(h0 + hh) * 1024 + r * 128 + k0 + tx] = (__bf16)t[tx][hh];
  }
}

__global__ __launch_bounds__(256) void k_cast(const float* __restrict__ src, __bf16* __restrict__ dst, int n4) {
  int i = blockIdx.x * 256 + threadIdx.x;
  if (i < n4) {
    float4 v = ((const float4*)src)[i];
    bf16x4 o;
    o.x = (__bf16)v.x; o.y = (__bf16)v.y; o.z = (__bf16)v.z; o.w = (__bf16)v.w;
    ((bf16x4*)dst)[i] = o;
  }
}

// qkv[n][c] = xb[n]·wqkb[c]  (c: 0-7 = qv per relation, 8-15 = kv).
// One wave per 16 nodes, 4x mfma_16x16x32_bf16 over K=128.
__global__ __launch_bounds__(256) void k_qkv(const __bf16* __restrict__ xb, const __bf16* __restrict__ wqkb,
                                             float* __restrict__ qkv, int N) {
  int wv = threadIdx.x >> 6, l = threadIdx.x & 63;
  int nb = blockIdx.x * 64 + wv * 16;
  if (nb >= N) return;
  int arow = nb + (l & 15);
  bool valid = arow < N;
  const bf16x8* gB = (const bf16x8*)(wqkb + (size_t)(l & 15) * 128 + (l >> 4) * 8);
  const bf16x8* gA = (const bf16x8*)(xb + (size_t)arow * 128 + (l >> 4) * 8);
  f32x4 acc = (f32x4)0.f;
  #pragma unroll
  for (int kt = 0; kt < 4; ++kt) {
    bf16x8 bv = gB[kt * 4];                        // +32 elems per kt
    bf16x8 av = valid ? gA[kt * 4] : (bf16x8)(__bf16)0.0f;
    acc = __builtin_amdgcn_mfma_f32_16x16x32_bf16(av, bv, acc, 0, 0, 0);
  }
  #pragma unroll
  for (int j = 0; j < 4; ++j) {
    int row = nb + (l >> 4) * 4 + j;
    if (row < N) qkv[(size_t)row * 16 + (l & 15)] = acc[j];
  }
}

// ------------------- softmax + gather aggregate (to agg) ---------------------
// One wave per node; LDS row accumulator [1024] f32 per wave.

__global__ __launch_bounds__(256) void k_agg2(const int* __restrict__ row_ptr, const int* __restrict__ recs,
                                              const float* __restrict__ qkv, const __bf16* __restrict__ xb,
                                              __bf16* __restrict__ agg, int N) {
  __shared__ float lacc[4][1024];
  int wv = threadIdx.x >> 6;
  int lane = threadIdx.x & 63;
  int n = blockIdx.x * 4 + wv;
  if (n >= N) return;
  float* A = lacc[wv];
  #pragma unroll
  for (int i = 0; i < 8; ++i)
    *(float2*)&A[i * 128 + 2 * lane] = make_float2(0.f, 0.f);

  int start = row_ptr[n], end = row_ptr[n + 1];
  const float* qvn = qkv + (size_t)n * 16;
  const bf16x2* xb2 = (const bf16x2*)xb;
  float denom = 0.f, m_run = -1e30f;

  for (int c0 = start; c0 < end; c0 += 64) {
    int cend = (end < c0 + 64) ? end : (c0 + 64);
    int cnt = cend - c0;
    int p = c0 + lane;
    float a = -1e30f; int rec = 0;
    if (p < cend) {
      rec = recs[p];
      int s = rec & 0x1FFFFF, r = (rec >> 21) & 7;
      float t = qvn[r] + qkv[(size_t)s * 16 + 8 + r];
      a = (t >= 0.f) ? t : 0.2f * t;
    }
    float cm = a;
    #pragma unroll
    for (int off = 32; off; off >>= 1) cm = fmaxf(cm, __shfl_xor(cm, off, 64));
    if (cm > m_run) {
      if (m_run > -1e29f) {
        float scale = __expf(m_run - cm);
        denom *= scale;
        #pragma unroll
        for (int i = 0; i < 8; ++i) {
          float2 c = *(float2*)&A[i * 128 + 2 * lane];
          c.x *= scale; c.y *= scale;
          *(float2*)&A[i * 128 + 2 * lane] = c;
        }
      }
      m_run = cm;
    }
    float wgt = (p < cend) ? __expf(a - m_run) : 0.f;
    float ws = wgt;
    #pragma unroll
    for (int off = 32; off; off >>= 1) ws += __shfl_xor(ws, off, 64);
    denom += ws;
    int wbits = __float_as_int(wgt);

#define RMW(RL, WW)                                                            \
    {                                                                          \
      int s_ = (RL) & 0x1FFFFF;                                                \
      int r_ = ((RL) >> 21) & 7;                                               \
      float fw = __int_as_float(WW);                                           \
      bf16x2 xv = xb2[(size_t)s_ * 64 + lane];                                 \
      float* ap = &A[r_ * 128 + 2 * lane];                                     \
      float2 c = *(float2*)ap;                                                 \
      c.x += fw * (float)xv.x;                                                 \
      c.y += fw * (float)xv.y;                                                 \
      *(float2*)ap = c;                                                        \
    }

    int e = 0;
    for (; e + 4 <= cnt; e += 4) {
      int rl0 = __builtin_amdgcn_readlane(rec, e + 0);
      int rl1 = __builtin_amdgcn_readlane(rec, e + 1);
      int rl2 = __builtin_amdgcn_readlane(rec, e + 2);
      int rl3 = __builtin_amdgcn_readlane(rec, e + 3);
      int w0 = __builtin_amdgcn_readlane(wbits, e + 0);
      int w1 = __builtin_amdgcn_readlane(wbits, e + 1);
      int w2 = __builtin_amdgcn_readlane(wbits, e + 2);
      int w3 = __builtin_amdgcn_readlane(wbits, e + 3);
      RMW(rl0, w0);
      RMW(rl1, w1);
      RMW(rl2, w2);
      RMW(rl3, w3);
    }
    for (; e < cnt; ++e) {
      int rl0 = __builtin_amdgcn_readlane(rec, e);
      int w0 = __builtin_amdgcn_readlane(wbits, e);
      RMW(rl0, w0);
    }
#undef RMW
  }

  float inv = 1.f / (denom + 1e-16f);
  bf16x2* ag2 = (bf16x2*)agg;
  size_t bptr = (size_t)n * 512;
  #pragma unroll
  for (int i = 0; i < 8; ++i) {
    float2 c = *(float2*)&A[i * 128 + 2 * lane];
    bf16x2 o;
    o.x = (__bf16)(c.x * inv);
    o.y = (__bf16)(c.y * inv);
    ag2[bptr + i * 64 + lane] = o;
  }
}

// --------------------------- MFMA GEMM (K=1024) ------------------------------

#define LSTR 72

__global__ __launch_bounds__(256) void k_gemm(const __bf16* __restrict__ A, const __bf16* __restrict__ B,
                                              const float* __restrict__ bias, __bf16* __restrict__ C, int M) {
  __shared__ __bf16 As[128 * LSTR];
  __shared__ __bf16 Bs[128 * LSTR];
  int bm = blockIdx.x * 128;
  int tid = threadIdx.x;
  int w = tid >> 6, l = tid & 63;

  f32x4 acc[2][8];
  #pragma unroll
  for (int m2 = 0; m2 < 2; ++m2)
    #pragma unroll
    for (int n2 = 0; n2 < 8; ++n2) acc[m2][n2] = (f32x4)0.f;

  int srow = tid >> 1;
  int cbase = (tid & 1) * 4;
  bool valid = (bm + srow) < M;
  const bf16x8* gA = (const bf16x8*)(A + (size_t)(bm + srow) * 1024);
  const bf16x8* gB = (const bf16x8*)(B + (size_t)srow * 1024);

  bf16x8 av[4], bv[4];
  #pragma unroll
  for (int i = 0; i < 4; ++i) {
    av[i] = valid ? gA[cbase + i] : (bf16x8)(__bf16)0.0f;
    bv[i] = gB[cbase + i];
  }

  for (int kt = 0; kt < 16; ++kt) {
    if (kt) __syncthreads();
    #pragma unroll
    for (int i = 0; i < 4; ++i) {
      *(bf16x8*)&As[srow * LSTR + (cbase + i) * 8] = av[i];
      *(bf16x8*)&Bs[srow * LSTR + (cbase + i) * 8] = bv[i];
    }
    __syncthreads();
    if (kt < 15) {
      #pragma unroll
      for (int i = 0; i < 4; ++i) {
        av[i] = valid ? gA[(kt + 1) * 8 + cbase + i] : (bf16x8)(__bf16)0.0f;
        bv[i] = gB[(kt + 1) * 8 + cbase + i];
      }
    }
    #pragma unroll
    for (int ks = 0; ks < 2; ++ks) {
      bf16x8 af[2], bfv[8];
      #pragma unroll
      for (int m2 = 0; m2 < 2; ++m2)
        af[m2] = *(const bf16x8*)&As[(w * 32 + m2 * 16 + (l & 15)) * LSTR + ks * 32 + (l >> 4) * 8];
      #pragma unroll
      for (int n2 = 0; n2 < 8; ++n2)
        bfv[n2] = *(const bf16x8*)&Bs[(n2 * 16 + (l & 15)) * LSTR + ks * 32 + (l >> 4) * 8];
      #pragma unroll
      for (int m2 = 0; m2 < 2; ++m2)
        #pragma unroll
        for (int n2 = 0; n2 < 8; ++n2)
          acc[m2][n2] = __builtin_amdgcn_mfma_f32_16x16x32_bf16(af[m2], bfv[n2], acc[m2][n2], 0, 0, 0);
    }
  }

  #pragma unroll
  for (int m2 = 0; m2 < 2; ++m2)
    #pragma unroll
    for (int j = 0; j < 4; ++j) {
      int row = w * 32 + m2 * 16 + (l >> 4) * 4 + j;
      if (bm + row < M) {
        #pragma unroll
        for (int n2 = 0; n2 < 8; ++n2) {
          float v = acc[m2][n2][j] + bias[n2 * 16 + (l & 15)];
          v = v > 0.f ? v : 0.f;
          C[(size_t)(bm + row) * 128 + n2 * 16 + (l & 15)] = (__bf16)v;
        }
      }
    }
}

// ------------------------------- pool + head ---------------------------------

__global__ __launch_bounds__(256) void k_pool(const __bf16* __restrict__ h, float* __restrict__ gsum,
                                              float* __restrict__ gmax, int N) {
  int c2 = threadIdx.x & 63;
  int grp = threadIdx.x >> 6;
  float s0 = 0.f, s1 = 0.f, m0 = 0.f, m1 = 0.f;
  for (int n = blockIdx.x * 4 + grp; n < N; n += gridDim.x * 4) {
    bf16x2 v = ((const bf16x2*)(h + (size_t)n * 128))[c2];
    float v0 = (float)v.x, v1 = (float)v.y;
    s0 += v0; s1 += v1;
    m0 = fmaxf(m0, v0); m1 = fmaxf(m1, v1);
  }
  __shared__ float ss0[256], ss1[256], sm0[256], sm1[256];
  ss0[threadIdx.x] = s0; ss1[threadIdx.x] = s1;
  sm0[threadIdx.x] = m0; sm1[threadIdx.x] = m1;
  __syncthreads();
  if (grp == 0) {
    #pragma unroll
    for (int g = 1; g < 4; ++g) {
      s0 += ss0[g * 64 + c2]; s1 += ss1[g * 64 + c2];
      m0 = fmaxf(m0, sm0[g * 64 + c2]); m1 = fmaxf(m1, sm1[g * 64 + c2]);
    }
    atomicAdd(&gsum[2 * c2 + 0], s0);
    atomicAdd(&gsum[2 * c2 + 1], s1);
    atomicMax((int*)gmax + 2 * c2 + 0, __float_as_int(m0));
    atomicMax((int*)gmax + 2 * c2 + 1, __float_as_int(m1));
  }
}

__global__ void k_head(const float* __restrict__ gsum, const float* __restrict__ gmax,
                       const float* __restrict__ fc1w, const float* __restrict__ fc1b,
                       const float* __restrict__ fc2w, const float* __restrict__ fc2b,
                       float* __restrict__ out, int N) {
  __shared__ float g[256];
  __shared__ float red[128];
  int t = threadIdx.x;
  if (t < 128) g[t] = tanhf(gsum[t] / (float)N);
  else g[t] = tanhf(gmax[t - 128]);
  __syncthreads();
  float r1 = 0.f;
  if (t < 128) {
    float a = fc1b[t];
    for (int i = 0; i < 256; i++) a += g[i] * fc1w[i * 128 + t];
    r1 = a > 0.f ? a : 0.f;
    red[t] = r1 * fc2w[t];
  }
  __syncthreads();
  for (int s = 64; s > 0; s >>= 1) {
    if (t < s) red[t] += red[t + s];
    __syncthreads();
  }
  if (t == 0) {
    float o = red[0] + fc2b[0];
    out[0] = 1.f / (1.f + __expf(-o));
  }
}

// --------------------------------- launch ------------------------------------

extern "C" void kernel_launch(void* const* d_in, const int* in_sizes, int n_in,
                              void* d_out, int out_size, void* d_ws, size_t ws_size,
                              hipStream_t stream) {
  const float* x    = (const float*)d_in[0];
  const int*   ei   = (const int*)d_in[1];
  const int*   ety  = (const int*)d_in[2];
  const float* w0   = (const float*)d_in[3];
  const float* q0   = (const float*)d_in[4];
  const float* k0   = (const float*)d_in[5];
  const float* b0   = (const float*)d_in[6];
  const float* w1   = (const float*)d_in[7];
  const float* q1   = (const float*)d_in[8];
  const float* k1   = (const float*)d_in[9];
  const float* b1   = (const float*)d_in[10];
  const float* fc1w = (const float*)d_in[11];
  const float* fc1b = (const float*)d_in[12];
  const float* fc2w = (const float*)d_in[13];
  const float* fc2b = (const float*)d_in[14];
  int N = in_sizes[0] / 128;
  int E = in_sizes[2];
  const int* src = ei;
  const int* dst = ei + E;

  char* base = (char*)d_ws;
  size_t off = 0;
  auto alloc = [&](size_t bytes) -> void* {
    off = (off + 255) & ~(size_t)255;
    void* p = base + off;
    off += bytes;
    return p;
  };
  int nb = (N + (1 << BSH) - 1) >> BSH;            // buckets of 16 nodes

  int*    row_ptr = (int*)alloc((size_t)(N + 1) * 4);
  int*    cnt     = (int*)alloc((size_t)N * 4);
  int*    bcur    = (int*)alloc((size_t)nb * 4);
  int*    tmp     = (int*)alloc((size_t)E * 4);    // binned packed records
  int*    recs    = (int*)alloc((size_t)E * 4);    // final CSR packed records
  int*    csums   = (int*)alloc(64 * 4);
  float*  qkv     = (float*)alloc((size_t)N * 16 * 4);
  float*  gsum    = (float*)alloc(128 * 4);
  float*  gmax    = (float*)alloc(128 * 4);
  __bf16* wqkb    = (__bf16*)alloc(2048 * 2);
  __bf16* xb      = (__bf16*)alloc((size_t)N * 128 * 2);
  __bf16* h1b     = (__bf16*)alloc((size_t)N * 128 * 2);
  __bf16* h2b     = (__bf16*)alloc((size_t)N * 128 * 2);
  __bf16* WT2     = (__bf16*)alloc((size_t)128 * 1024 * 2);
  __bf16* agg     = (__bf16*)alloc((size_t)N * 1024 * 2);

  // CSR build
  int nchunks = (N + SCHUNK - 1) / SCHUNK;
  hipMemsetAsync(cnt, 0, (size_t)N * 4, stream);
  k_hist<<<(E + 255) / 256, 256, 0, stream>>>(dst, cnt, E);
  k_chunk_sums<<<nchunks, 256, 0, stream>>>(cnt, csums, N);
  k_scan_sums<<<1, 64, 0, stream>>>(csums, nchunks);
  k_scan_write<<<nchunks, 256, 0, stream>>>(cnt, csums, row_ptr, N, E);
  k_binit<<<(nb + 255) / 256, 256, 0, stream>>>(row_ptr, bcur, nb, N);
  k_binscatter<<<(E + 255) / 256, 256, 0, stream>>>(src, dst, ety, bcur, tmp, E);
  k_binsort<<<nb, 256, 0, stream>>>(row_ptr, tmp, recs, N, E);

  k_cast<<<((N * 32) + 255) / 256, 256, 0, stream>>>(x, xb, N * 32);

  for (int layer = 0; layer < 2; ++layer) {
    const float*  W    = layer ? w1 : w0;
    const float*  qq   = layer ? q1 : q0;
    const float*  kk   = layer ? k1 : k0;
    const float*  bb   = layer ? b1 : b0;
    const __bf16* xinb = layer ? h1b : xb;
    __bf16*       hout = layer ? h2b : h1b;

    k_wqk<<<256, 256, 0, stream>>>(W, qq, kk, wqkb);
    k_qkv<<<(N + 63) / 64, 256, 0, stream>>>(xinb, wqkb, qkv, N);
    {
      dim3 g(4, 4, 8);
      k_wt<<<g, 256, 0, stream>>>(W, WT2);
    }
    k_agg2<<<(N + 3) / 4, 256, 0, stream>>>(row_ptr, recs, qkv, xinb, agg, N);
    k_gemm<<<(N + 127) / 128, 256, 0, stream>>>(agg, WT2, bb, hout, N);
  }

  hipMemsetAsync(gsum, 0, 128 * 4, stream);
  hipMemsetAsync(gmax, 0, 128 * 4, stream);
  k_pool<<<256, 256, 0, stream>>>(h2b, gsum, gmax, N);
  k_head<<<1, 256, 0, stream>>>(gsum, gmax, fc1w, fc1b, fc2w, fc2b, (float*)d_out, N);
}

// Round 6
// 292.673 us; speedup vs baseline: 3.1999x; 1.2431x over previous
//
#include <hip/hip_runtime.h>
#include <hip/hip_bf16.h>

// ---------------------------------------------------------------------------
// RGAT: 2x RGATConv (R=8, H=128) + mean/max pool + MLP head -> scalar
//
// R6 structure:
//   CSR build (2-level bucket sort, block-owned write windows):
//     k_chist: LDS histogram of coarse buckets (dst>>10)
//     k_cscan: exclusive scan -> cbase/ccur
//     k_cscatter: block groups 4096 edges by bucket in LDS, flushes
//                 contiguous runs (kills write amplification)
//     k_fsort: block per coarse bucket; per-node LDS histogram + scan ->
//              row_ptr + final records, writes confined to 64KB window
//   per layer:
//     k_wqk:  wqkb[16][128] = bf16(concat(W[r]@q, W[r]@k))
//     k_qkv:  qkv[N][16] = xb @ wqkb^T   (MFMA)
//     k_agg2: 1 wave/node; online-softmax lane-parallel; LDS row accumulator
//     k_gemm: h = relu(agg[N,1024] @ Wcat[1024,128] + b)  (bf16 MFMA)
//   pool (mean+max) -> tanh -> fc1 relu -> fc2 -> sigmoid
//
// Record packing: rec = src | et<<17 | dlow<<20   (N < 2^17, dlow = dst&1023)
// ---------------------------------------------------------------------------

typedef __bf16 bf16x8 __attribute__((ext_vector_type(8)));
typedef __bf16 bf16x4 __attribute__((ext_vector_type(4)));
typedef __bf16 bf16x2 __attribute__((ext_vector_type(2)));
typedef float f32x4 __attribute__((ext_vector_type(4)));

#define CBSH 10                 // coarse bucket = 1024 nodes
#define CSC_CH 4096             // edges per cscatter block

// ----------------------------- CSR build -----------------------------------

__global__ __launch_bounds__(256) void k_chist(const int* __restrict__ dst, int* __restrict__ chist, int E) {
  __shared__ int lh[64];
  int t = threadIdx.x;
  if (t < 64) lh[t] = 0;
  __syncthreads();
  for (int e = blockIdx.x * 256 + t; e < E; e += gridDim.x * 256)
    atomicAdd(&lh[dst[e] >> CBSH], 1);
  __syncthreads();
  if (t < 64 && lh[t]) atomicAdd(&chist[t], lh[t]);
}

__global__ void k_cscan(const int* __restrict__ chist, int* __restrict__ cbase, int* __restrict__ ccur,
                        int ncb, int E) {
  if (threadIdx.x == 0) {
    int acc = 0;
    for (int i = 0; i < ncb; ++i) { cbase[i] = acc; ccur[i] = acc; acc += chist[i]; }
    cbase[ncb] = E;
  }
}

__global__ __launch_bounds__(256) void k_cscatter(const int* __restrict__ src, const int* __restrict__ dst,
                                                  const int* __restrict__ et, int* __restrict__ ccur,
                                                  int* __restrict__ tmp, int E) {
  __shared__ int recbuf[CSC_CH];
  __shared__ int lcnt[64], lbase[64], gbase[64], lcur[64];
  int t = threadIdx.x;
  int base = blockIdx.x * CSC_CH;
  int cnt = E - base; if (cnt > CSC_CH) cnt = CSC_CH;
  if (t < 64) lcnt[t] = 0;
  __syncthreads();
  int myrec[CSC_CH / 256], mycb[CSC_CH / 256];
  int k = 0;
  for (int i = t; i < cnt; i += 256, ++k) {
    int d = dst[base + i];
    int cb = d >> CBSH;
    myrec[k] = src[base + i] | (et[base + i] << 17) | ((d & ((1 << CBSH) - 1)) << 20);
    mycb[k] = cb;
    atomicAdd(&lcnt[cb], 1);
  }
  __syncthreads();
  if (t == 0) {
    int acc = 0;
    for (int c = 0; c < 64; ++c) { lbase[c] = acc; lcur[c] = acc; acc += lcnt[c]; }
  }
  __syncthreads();
  if (t < 64 && lcnt[t] > 0) gbase[t] = atomicAdd(&ccur[t], lcnt[t]);
  __syncthreads();
  k = 0;
  for (int i = t; i < cnt; i += 256, ++k) {
    int p = atomicAdd(&lcur[mycb[k]], 1);
    recbuf[p] = myrec[k];
  }
  __syncthreads();
  for (int i = t; i < cnt; i += 256) {
    int lo = 0, hi = 63;                          // largest c with lbase[c] <= i
    while (lo < hi) { int mid = (lo + hi + 1) >> 1; if (lbase[mid] <= i) lo = mid; else hi = mid - 1; }
    tmp[gbase[lo] + (i - lbase[lo])] = recbuf[i];
  }
}

// block per coarse bucket: per-node histogram + scan -> row_ptr + final recs
__global__ __launch_bounds__(1024) void k_fsort(const int* __restrict__ cbase, const int* __restrict__ tmp,
                                                int* __restrict__ recs, int* __restrict__ row_ptr,
                                                int N, int E) {
  __shared__ int sd[1024];
  __shared__ int ncur[1024];
  int cb = blockIdx.x, t = threadIdx.x;
  int n0 = cb << CBSH;
  int begin = cbase[cb], endd = cbase[cb + 1];
  sd[t] = 0;
  __syncthreads();
  for (int i = begin + t; i < endd; i += 1024)
    atomicAdd(&sd[(tmp[i] >> 20) & 1023], 1);
  __syncthreads();
  int myc = sd[t];
  for (int off = 1; off < 1024; off <<= 1) {
    int xv = 0; if (t >= off) xv = sd[t - off];
    __syncthreads();
    sd[t] += xv;
    __syncthreads();
  }
  int ex = sd[t] - myc;                            // exclusive prefix
  int node = n0 + t;
  if (node < N) row_ptr[node] = begin + ex;
  if (node == N - 1) row_ptr[N] = E;
  ncur[t] = begin + ex;
  __syncthreads();
  for (int i = begin + t; i < endd; i += 1024) {
    int rc = tmp[i];
    int p = atomicAdd(&ncur[(rc >> 20) & 1023], 1);
    recs[p] = rc & 0xFFFFF;                        // src | et<<17
  }
}

// ----------------------------- small precompute ------------------------------

// wqkb[c][i], c<8: W[c][i][:]·q ; c>=8: W[c-8][i][:]·k.  One wave per (r,i) row.
__global__ __launch_bounds__(256) void k_wqk(const float* __restrict__ W, const float* __restrict__ q,
                                             const float* __restrict__ k, __bf16* __restrict__ wqkb) {
  int g = blockIdx.x * 4 + (threadIdx.x >> 6);
  int lane = threadIdx.x & 63;
  if (g >= 1024) return;
  const float2* wrow = (const float2*)(W + (size_t)g * 128);
  float2 wv = wrow[lane];
  float2 qv2 = ((const float2*)q)[lane];
  float2 kv2 = ((const float2*)k)[lane];
  float aq = wv.x * qv2.x + wv.y * qv2.y;
  float ak = wv.x * kv2.x + wv.y * kv2.y;
  #pragma unroll
  for (int off = 32; off; off >>= 1) {
    aq += __shfl_xor(aq, off, 64);
    ak += __shfl_xor(ak, off, 64);
  }
  if (lane == 0) { wqkb[g] = (__bf16)aq; wqkb[1024 + g] = (__bf16)ak; }
}

// WT2[h][r*128+k] = bf16(W[r][k][h]) via LDS 32x32 tile transpose.
__global__ __launch_bounds__(256) void k_wt(const float* __restrict__ W, __bf16* __restrict__ WT) {
  __shared__ float t[32][33];
  int r = blockIdx.z;
  int k0 = blockIdx.x * 32, h0 = blockIdx.y * 32;
  int tx = threadIdx.x & 31;
  int ty = threadIdx.x >> 5;
  #pragma unroll
  for (int i = 0; i < 4; ++i) {
    int kk = ty + i * 8;
    t[kk][tx] = W[((size_t)r * 128 + k0 + kk) * 128 + h0 + tx];
  }
  __syncthreads();
  #pragma unroll
  for (int i = 0; i < 4; ++i) {
    int hh = ty + i * 8;
    WT[(size_t)(h0 + hh) * 1024 + r * 128 + k0 + tx] = (__bf16)t[tx][hh];
  }
}

__global__ __launch_bounds__(256) void k_cast(const float* __restrict__ src, __bf16* __restrict__ dst, int n4) {
  int i = blockIdx.x * 256 + threadIdx.x;
  if (i < n4) {
    float4 v = ((const float4*)src)[i];
    bf16x4 o;
    o.x = (__bf16)v.x; o.y = (__bf16)v.y; o.z = (__bf16)v.z; o.w = (__bf16)v.w;
    ((bf16x4*)dst)[i] = o;
  }
}

// qkv[n][c] = xb[n]·wqkb[c]  (c: 0-7 = qv per relation, 8-15 = kv).
__global__ __launch_bounds__(256) void k_qkv(const __bf16* __restrict__ xb, const __bf16* __restrict__ wqkb,
                                             float* __restrict__ qkv, int N) {
  int wv = threadIdx.x >> 6, l = threadIdx.x & 63;
  int nb = blockIdx.x * 64 + wv * 16;
  if (nb >= N) return;
  int arow = nb + (l & 15);
  bool valid = arow < N;
  const bf16x8* gB = (const bf16x8*)(wqkb + (size_t)(l & 15) * 128 + (l >> 4) * 8);
  const bf16x8* gA = (const bf16x8*)(xb + (size_t)arow * 128 + (l >> 4) * 8);
  f32x4 acc = (f32x4)0.f;
  #pragma unroll
  for (int kt = 0; kt < 4; ++kt) {
    bf16x8 bv = gB[kt * 4];
    bf16x8 av = valid ? gA[kt * 4] : (bf16x8)(__bf16)0.0f;
    acc = __builtin_amdgcn_mfma_f32_16x16x32_bf16(av, bv, acc, 0, 0, 0);
  }
  #pragma unroll
  for (int j = 0; j < 4; ++j) {
    int row = nb + (l >> 4) * 4 + j;
    if (row < N) qkv[(size_t)row * 16 + (l & 15)] = acc[j];
  }
}

// ------------------- softmax + gather aggregate (to agg) ---------------------
// One wave per node; LDS row accumulator [1024] f32 per wave.

__global__ __launch_bounds__(256) void k_agg2(const int* __restrict__ row_ptr, const int* __restrict__ recs,
                                              const float* __restrict__ qkv, const __bf16* __restrict__ xb,
                                              __bf16* __restrict__ agg, int N) {
  __shared__ float lacc[4][1024];
  int wv = threadIdx.x >> 6;
  int lane = threadIdx.x & 63;
  int n = blockIdx.x * 4 + wv;
  if (n >= N) return;
  float* A = lacc[wv];
  #pragma unroll
  for (int i = 0; i < 8; ++i)
    *(float2*)&A[i * 128 + 2 * lane] = make_float2(0.f, 0.f);

  int start = row_ptr[n], end = row_ptr[n + 1];
  const float* qvn = qkv + (size_t)n * 16;
  const bf16x2* xb2 = (const bf16x2*)xb;
  float denom = 0.f, m_run = -1e30f;

  for (int c0 = start; c0 < end; c0 += 64) {
    int cend = (end < c0 + 64) ? end : (c0 + 64);
    int cnt = cend - c0;
    int p = c0 + lane;
    float a = -1e30f; int rec = 0;
    if (p < cend) {
      rec = recs[p];
      int s = rec & 0x1FFFF, r = (rec >> 17) & 7;
      float t = qvn[r] + qkv[(size_t)s * 16 + 8 + r];
      a = (t >= 0.f) ? t : 0.2f * t;
    }
    float cm = a;
    #pragma unroll
    for (int off = 32; off; off >>= 1) cm = fmaxf(cm, __shfl_xor(cm, off, 64));
    if (cm > m_run) {
      if (m_run > -1e29f) {
        float scale = __expf(m_run - cm);
        denom *= scale;
        #pragma unroll
        for (int i = 0; i < 8; ++i) {
          float2 c = *(float2*)&A[i * 128 + 2 * lane];
          c.x *= scale; c.y *= scale;
          *(float2*)&A[i * 128 + 2 * lane] = c;
        }
      }
      m_run = cm;
    }
    float wgt = (p < cend) ? __expf(a - m_run) : 0.f;
    float ws = wgt;
    #pragma unroll
    for (int off = 32; off; off >>= 1) ws += __shfl_xor(ws, off, 64);
    denom += ws;
    int wbits = __float_as_int(wgt);

#define RMW(RL, WW)                                                            \
    {                                                                          \
      int s_ = (RL) & 0x1FFFF;                                                 \
      int r_ = ((RL) >> 17) & 7;                                               \
      float fw = __int_as_float(WW);                                           \
      bf16x2 xv = xb2[(size_t)s_ * 64 + lane];                                 \
      float* ap = &A[r_ * 128 + 2 * lane];                                     \
      float2 c = *(float2*)ap;                                                 \
      c.x += fw * (float)xv.x;                                                 \
      c.y += fw * (float)xv.y;                                                 \
      *(float2*)ap = c;                                                        \
    }

    int e = 0;
    for (; e + 4 <= cnt; e += 4) {
      int rl0 = __builtin_amdgcn_readlane(rec, e + 0);
      int rl1 = __builtin_amdgcn_readlane(rec, e + 1);
      int rl2 = __builtin_amdgcn_readlane(rec, e + 2);
      int rl3 = __builtin_amdgcn_readlane(rec, e + 3);
      int w0 = __builtin_amdgcn_readlane(wbits, e + 0);
      int w1 = __builtin_amdgcn_readlane(wbits, e + 1);
      int w2 = __builtin_amdgcn_readlane(wbits, e + 2);
      int w3 = __builtin_amdgcn_readlane(wbits, e + 3);
      RMW(rl0, w0);
      RMW(rl1, w1);
      RMW(rl2, w2);
      RMW(rl3, w3);
    }
    for (; e < cnt; ++e) {
      int rl0 = __builtin_amdgcn_readlane(rec, e);
      int w0 = __builtin_amdgcn_readlane(wbits, e);
      RMW(rl0, w0);
    }
#undef RMW
  }

  float inv = 1.f / (denom + 1e-16f);
  bf16x2* ag2 = (bf16x2*)agg;
  size_t bptr = (size_t)n * 512;
  #pragma unroll
  for (int i = 0; i < 8; ++i) {
    float2 c = *(float2*)&A[i * 128 + 2 * lane];
    bf16x2 o;
    o.x = (__bf16)(c.x * inv);
    o.y = (__bf16)(c.y * inv);
    ag2[bptr + i * 64 + lane] = o;
  }
}

// --------------------------- MFMA GEMM (K=1024) ------------------------------

#define LSTR 72

__global__ __launch_bounds__(256) void k_gemm(const __bf16* __restrict__ A, const __bf16* __restrict__ B,
                                              const float* __restrict__ bias, __bf16* __restrict__ C, int M) {
  __shared__ __bf16 As[128 * LSTR];
  __shared__ __bf16 Bs[128 * LSTR];
  int bm = blockIdx.x * 128;
  int tid = threadIdx.x;
  int w = tid >> 6, l = tid & 63;

  f32x4 acc[2][8];
  #pragma unroll
  for (int m2 = 0; m2 < 2; ++m2)
    #pragma unroll
    for (int n2 = 0; n2 < 8; ++n2) acc[m2][n2] = (f32x4)0.f;

  int srow = tid >> 1;
  int cbase = (tid & 1) * 4;
  bool valid = (bm + srow) < M;
  const bf16x8* gA = (const bf16x8*)(A + (size_t)(bm + srow) * 1024);
  const bf16x8* gB = (const bf16x8*)(B + (size_t)srow * 1024);

  bf16x8 av[4], bv[4];
  #pragma unroll
  for (int i = 0; i < 4; ++i) {
    av[i] = valid ? gA[cbase + i] : (bf16x8)(__bf16)0.0f;
    bv[i] = gB[cbase + i];
  }

  for (int kt = 0; kt < 16; ++kt) {
    if (kt) __syncthreads();
    #pragma unroll
    for (int i = 0; i < 4; ++i) {
      *(bf16x8*)&As[srow * LSTR + (cbase + i) * 8] = av[i];
      *(bf16x8*)&Bs[srow * LSTR + (cbase + i) * 8] = bv[i];
    }
    __syncthreads();
    if (kt < 15) {
      #pragma unroll
      for (int i = 0; i < 4; ++i) {
        av[i] = valid ? gA[(kt + 1) * 8 + cbase + i] : (bf16x8)(__bf16)0.0f;
        bv[i] = gB[(kt + 1) * 8 + cbase + i];
      }
    }
    #pragma unroll
    for (int ks = 0; ks < 2; ++ks) {
      bf16x8 af[2], bfv[8];
      #pragma unroll
      for (int m2 = 0; m2 < 2; ++m2)
        af[m2] = *(const bf16x8*)&As[(w * 32 + m2 * 16 + (l & 15)) * LSTR + ks * 32 + (l >> 4) * 8];
      #pragma unroll
      for (int n2 = 0; n2 < 8; ++n2)
        bfv[n2] = *(const bf16x8*)&Bs[(n2 * 16 + (l & 15)) * LSTR + ks * 32 + (l >> 4) * 8];
      #pragma unroll
      for (int m2 = 0; m2 < 2; ++m2)
        #pragma unroll
        for (int n2 = 0; n2 < 8; ++n2)
          acc[m2][n2] = __builtin_amdgcn_mfma_f32_16x16x32_bf16(af[m2], bfv[n2], acc[m2][n2], 0, 0, 0);
    }
  }

  #pragma unroll
  for (int m2 = 0; m2 < 2; ++m2)
    #pragma unroll
    for (int j = 0; j < 4; ++j) {
      int row = w * 32 + m2 * 16 + (l >> 4) * 4 + j;
      if (bm + row < M) {
        #pragma unroll
        for (int n2 = 0; n2 < 8; ++n2) {
          float v = acc[m2][n2][j] + bias[n2 * 16 + (l & 15)];
          v = v > 0.f ? v : 0.f;
          C[(size_t)(bm + row) * 128 + n2 * 16 + (l & 15)] = (__bf16)v;
        }
      }
    }
}

// ------------------------------- pool + head ---------------------------------

__global__ __launch_bounds__(256) void k_pool(const __bf16* __restrict__ h, float* __restrict__ gsum,
                                              float* __restrict__ gmax, int N) {
  int c2 = threadIdx.x & 63;
  int grp = threadIdx.x >> 6;
  float s0 = 0.f, s1 = 0.f, m0 = 0.f, m1 = 0.f;
  for (int n = blockIdx.x * 4 + grp; n < N; n += gridDim.x * 4) {
    bf16x2 v = ((const bf16x2*)(h + (size_t)n * 128))[c2];
    float v0 = (float)v.x, v1 = (float)v.y;
    s0 += v0; s1 += v1;
    m0 = fmaxf(m0, v0); m1 = fmaxf(m1, v1);
  }
  __shared__ float ss0[256], ss1[256], sm0[256], sm1[256];
  ss0[threadIdx.x] = s0; ss1[threadIdx.x] = s1;
  sm0[threadIdx.x] = m0; sm1[threadIdx.x] = m1;
  __syncthreads();
  if (grp == 0) {
    #pragma unroll
    for (int g = 1; g < 4; ++g) {
      s0 += ss0[g * 64 + c2]; s1 += ss1[g * 64 + c2];
      m0 = fmaxf(m0, sm0[g * 64 + c2]); m1 = fmaxf(m1, sm1[g * 64 + c2]);
    }
    atomicAdd(&gsum[2 * c2 + 0], s0);
    atomicAdd(&gsum[2 * c2 + 1], s1);
    atomicMax((int*)gmax + 2 * c2 + 0, __float_as_int(m0));
    atomicMax((int*)gmax + 2 * c2 + 1, __float_as_int(m1));
  }
}

__global__ void k_head(const float* __restrict__ gsum, const float* __restrict__ gmax,
                       const float* __restrict__ fc1w, const float* __restrict__ fc1b,
                       const float* __restrict__ fc2w, const float* __restrict__ fc2b,
                       float* __restrict__ out, int N) {
  __shared__ float g[256];
  __shared__ float red[128];
  int t = threadIdx.x;
  if (t < 128) g[t] = tanhf(gsum[t] / (float)N);
  else g[t] = tanhf(gmax[t - 128]);
  __syncthreads();
  float r1 = 0.f;
  if (t < 128) {
    float a = fc1b[t];
    for (int i = 0; i < 256; i++) a += g[i] * fc1w[i * 128 + t];
    r1 = a > 0.f ? a : 0.f;
    red[t] = r1 * fc2w[t];
  }
  __syncthreads();
  for (int s = 64; s > 0; s >>= 1) {
    if (t < s) red[t] += red[t + s];
    __syncthreads();
  }
  if (t == 0) {
    float o = red[0] + fc2b[0];
    out[0] = 1.f / (1.f + __expf(-o));
  }
}

// --------------------------------- launch ------------------------------------

extern "C" void kernel_launch(void* const* d_in, const int* in_sizes, int n_in,
                              void* d_out, int out_size, void* d_ws, size_t ws_size,
                              hipStream_t stream) {
  const float* x    = (const float*)d_in[0];
  const int*   ei   = (const int*)d_in[1];
  const int*   ety  = (const int*)d_in[2];
  const float* w0   = (const float*)d_in[3];
  const float* q0   = (const float*)d_in[4];
  const float* k0   = (const float*)d_in[5];
  const float* b0   = (const float*)d_in[6];
  const float* w1   = (const float*)d_in[7];
  const float* q1   = (const float*)d_in[8];
  const float* k1   = (const float*)d_in[9];
  const float* b1   = (const float*)d_in[10];
  const float* fc1w = (const float*)d_in[11];
  const float* fc1b = (const float*)d_in[12];
  const float* fc2w = (const float*)d_in[13];
  const float* fc2b = (const float*)d_in[14];
  int N = in_sizes[0] / 128;
  int E = in_sizes[2];
  const int* src = ei;
  const int* dst = ei + E;

  char* base = (char*)d_ws;
  size_t off = 0;
  auto alloc = [&](size_t bytes) -> void* {
    off = (off + 255) & ~(size_t)255;
    void* p = base + off;
    off += bytes;
    return p;
  };
  int ncb = (N + (1 << CBSH) - 1) >> CBSH;         // coarse buckets (<=64)

  int*    row_ptr = (int*)alloc((size_t)(N + 1) * 4);
  int*    chist   = (int*)alloc(64 * 4);
  int*    cbase   = (int*)alloc(65 * 4);
  int*    ccur    = (int*)alloc(64 * 4);
  int*    tmp     = (int*)alloc((size_t)E * 4);
  int*    recs    = (int*)alloc((size_t)E * 4);
  float*  qkv     = (float*)alloc((size_t)N * 16 * 4);
  float*  gsum    = (float*)alloc(128 * 4);
  float*  gmax    = (float*)alloc(128 * 4);
  __bf16* wqkb    = (__bf16*)alloc(2048 * 2);
  __bf16* xb      = (__bf16*)alloc((size_t)N * 128 * 2);
  __bf16* h1b     = (__bf16*)alloc((size_t)N * 128 * 2);
  __bf16* h2b     = (__bf16*)alloc((size_t)N * 128 * 2);
  __bf16* WT2     = (__bf16*)alloc((size_t)128 * 1024 * 2);
  __bf16* agg     = (__bf16*)alloc((size_t)N * 1024 * 2);

  // CSR build
  hipMemsetAsync(chist, 0, 64 * 4, stream);
  k_chist<<<256, 256, 0, stream>>>(dst, chist, E);
  k_cscan<<<1, 64, 0, stream>>>(chist, cbase, ccur, ncb, E);
  k_cscatter<<<(E + CSC_CH - 1) / CSC_CH, 256, 0, stream>>>(src, dst, ety, ccur, tmp, E);
  k_fsort<<<ncb, 1024, 0, stream>>>(cbase, tmp, recs, row_ptr, N, E);

  k_cast<<<((N * 32) + 255) / 256, 256, 0, stream>>>(x, xb, N * 32);

  for (int layer = 0; layer < 2; ++layer) {
    const float*  W    = layer ? w1 : w0;
    const float*  qq   = layer ? q1 : q0;
    const float*  kk   = layer ? k1 : k0;
    const float*  bb   = layer ? b1 : b0;
    const __bf16* xinb = layer ? h1b : xb;
    __bf16*       hout = layer ? h2b : h1b;

    k_wqk<<<256, 256, 0, stream>>>(W, qq, kk, wqkb);
    k_qkv<<<(N + 63) / 64, 256, 0, stream>>>(xinb, wqkb, qkv, N);
    {
      dim3 g(4, 4, 8);
      k_wt<<<g, 256, 0, stream>>>(W, WT2);
    }
    k_agg2<<<(N + 3) / 4, 256, 0, stream>>>(row_ptr, recs, qkv, xinb, agg, N);
    k_gemm<<<(N + 127) / 128, 256, 0, stream>>>(agg, WT2, bb, hout, N);
  }

  hipMemsetAsync(gsum, 0, 128 * 4, stream);
  hipMemsetAsync(gmax, 0, 128 * 4, stream);
  k_pool<<<256, 256, 0, stream>>>(h2b, gsum, gmax, N);
  k_head<<<1, 256, 0, stream>>>(gsum, gmax, fc1w, fc1b, fc2w, fc2b, (float*)d_out, N);
}